// Round 10
// baseline (217.031 us; speedup 1.0000x reference)
//
#include <hip/hip_runtime.h>
#include <math.h>

#define N_NODES 100000
#define N_EDGES 1600000
#define F_IN 128
#define H_DIM 128
#define C_OUT 40
#define BN_EPS 1e-5f

#define ELL_W 64           // slots per node; Poisson(16) => P(deg>63) ~ 1e-17
#define CNT_STRIDE 16      // bcur padding: one cursor per 64B line

#define BKT_W 512          // nodes per coarse bucket
#define NBKT ((N_NODES + BKT_W - 1) / BKT_W)            // 196
#define BKT_CAP 12288      // edges capacity per bucket (mean 8163, +45 sigma)
#define P_EDGES 2048       // edges per scatter block
#define P_NB ((N_EDGES + P_EDGES - 1) / P_EDGES)        // 782

#define G1_ROWS 128
#define G1_LD 136          // shorts: 272 B row
#define G1_NB ((N_NODES + G1_ROWS - 1) / G1_ROWS)       // 782
#define PS_LD 800          // pstats stride (>= G1_NB)
#define G2_ROWS 128
#define G2_NB ((N_NODES + G2_ROWS - 1) / G2_ROWS)       // 782

typedef unsigned short u16;
typedef unsigned int u32;
typedef __attribute__((ext_vector_type(8))) __bf16 bf16x8;
typedef __attribute__((ext_vector_type(4))) float f32x4;

__device__ __forceinline__ u16 f2bf(float f) {              // RNE
    u32 u = __float_as_uint(f);
    u += 0x7FFFu + ((u >> 16) & 1u);
    return (u16)(u >> 16);
}
__device__ __forceinline__ float bf2f(u16 h) {
    return __uint_as_float(((u32)h) << 16);
}
// packed dword of 2 bf16 -> two f32 adds (2 VALU each)
__device__ __forceinline__ void add2(float* a0, float* a1, u32 d) {
    *a0 += __uint_as_float(d << 16);
    *a1 += __uint_as_float(d & 0xFFFF0000u);
}
#define ACC4(v) do { add2(&acc[0],&acc[1],(u32)(v).x); add2(&acc[2],&acc[3],(u32)(v).y); \
                     add2(&acc[4],&acc[5],(u32)(v).z); add2(&acc[6],&acc[7],(u32)(v).w); } while(0)

// ---- pass 1: bucket edges by dst>>9 into per-bucket regions (coalesced-ish)
__global__ __launch_bounds__(256) void bucket_scatter(const int* __restrict__ src,
                                                      const int* __restrict__ dst,
                                                      int* __restrict__ bcur,
                                                      int2* __restrict__ region) {
    __shared__ int lcnt[NBKT];
    __shared__ int gofs[NBKT];
    int t = threadIdx.x;
    for (int i = t; i < NBKT; i += 256) lcnt[i] = 0;
    __syncthreads();
    int base = blockIdx.x * P_EDGES;
    int d[8], bk[8];
    #pragma unroll
    for (int i = 0; i < 8; ++i) {
        int idx = base + i * 256 + t;
        if (idx < N_EDGES) {
            d[i] = dst[idx];
            bk[i] = d[i] >> 9;
            atomicAdd(&lcnt[bk[i]], 1);
        } else d[i] = -1;
    }
    __syncthreads();
    for (int i = t; i < NBKT; i += 256) {
        int c = lcnt[i];
        gofs[i] = c ? atomicAdd(&bcur[i * CNT_STRIDE], c) : 0;
        lcnt[i] = 0;                      // reuse as local rank counter
    }
    __syncthreads();
    #pragma unroll
    for (int i = 0; i < 8; ++i) {
        int idx = base + i * 256 + t;
        if (idx < N_EDGES) {
            int rank = atomicAdd(&lcnt[bk[i]], 1);
            int pos = gofs[bk[i]] + rank;
            if (pos < BKT_CAP)            // statistically impossible; guards OOB
                region[(size_t)bk[i] * BKT_CAP + pos] = make_int2(src[idx], d[i]);
        }
    }
}

// ---- pass 2: per-bucket ELL build; scatter confined to a 128KB window ----
__global__ __launch_bounds__(256) void ell_build(const int* __restrict__ bcur,
                                                 const int2* __restrict__ region,
                                                 int* __restrict__ ell,
                                                 int* __restrict__ cnt,
                                                 float* __restrict__ dinv) {
    __shared__ int lcnt[BKT_W];
    int b = blockIdx.x, t = threadIdx.x;
    int nbase = b * BKT_W;
    for (int i = t; i < BKT_W; i += 256) {
        lcnt[i] = 1;                      // self-loop occupies slot 0
        int node = nbase + i;
        if (node < N_NODES) ell[(size_t)node * ELL_W] = node;
    }
    __syncthreads();
    int ne = bcur[b * CNT_STRIDE];
    if (ne > BKT_CAP) ne = BKT_CAP;
    const int2* reg = region + (size_t)b * BKT_CAP;
    for (int i = t; i < ne; i += 256) {
        int2 p = reg[i];
        int rank = atomicAdd(&lcnt[p.y - nbase], 1);
        if (rank < ELL_W) ell[(size_t)p.y * ELL_W + rank] = p.x;
    }
    __syncthreads();
    for (int i = t; i < BKT_W; i += 256) {
        int node = nbase + i;
        if (node < N_NODES) {
            int c = lcnt[i];
            cnt[node] = (c > ELL_W) ? ELL_W : c;
            dinv[node] = rsqrtf((float)c);   // true degree
        }
    }
}

// ---------------- xs = dinv[n] * x (bf16, RNE) ----------------
__global__ __launch_bounds__(256) void xconvert(const float* __restrict__ x,
                                                const float* __restrict__ dinv,
                                                u16* __restrict__ xs) {
    int i = blockIdx.x * 256 + threadIdx.x;      // exactly 3.2M threads (float4 units)
    int n = i >> 5;                              // 32 float4 per row
    float dd = dinv[n];
    float4 v = ((const float4*)x)[i];
    ushort4 o;
    o.x = f2bf(v.x * dd); o.y = f2bf(v.y * dd);
    o.z = f2bf(v.z * dd); o.w = f2bf(v.w * dd);
    ((ushort4*)xs)[i] = o;
}

// W1 [k][n] f32 -> W1t [n][k] bf16
__global__ __launch_bounds__(256) void wconvert(const float* __restrict__ W1,
                                                u16* __restrict__ W1t) {
    int i = blockIdx.x * 256 + threadIdx.x;      // 16384
    int k = i >> 7, n = i & 127;
    W1t[n * H_DIM + k] = f2bf(W1[k * H_DIM + n]);
}

// ------- gather layer 1, channel-split 2-pass (blockIdx.y = half) ----------
// 8 lanes/node (8 ch each, int4 = 64 ch/half), 32 nodes/block, 8-edge unroll.
// Halves the random working set per pass (25.6 -> 12.8 MB) for L2 residency.
__global__ __launch_bounds__(256) void gather_x(const int* __restrict__ cnt,
                                                const int* __restrict__ ell,
                                                const float* __restrict__ dinv,
                                                const u16* __restrict__ xs,
                                                u16* __restrict__ aggb) {
    int node = blockIdx.x * 32 + (threadIdx.x >> 3);     // grid exact: N%32==0
    int h = blockIdx.y;                                  // channel half 0/1
    int q = threadIdx.x & 7;
    int len = cnt[node];
    const int* rowp = ell + (size_t)node * ELL_W;
    const u16* xb = xs + h * 64 + q * 8;
    float acc[8] = {};
    int e = 0;
    for (; e + 7 < len; e += 8) {
        int4 v0 = *(const int4*)(xb + (size_t)rowp[e + 0] * F_IN);
        int4 v1 = *(const int4*)(xb + (size_t)rowp[e + 1] * F_IN);
        int4 v2 = *(const int4*)(xb + (size_t)rowp[e + 2] * F_IN);
        int4 v3 = *(const int4*)(xb + (size_t)rowp[e + 3] * F_IN);
        int4 v4 = *(const int4*)(xb + (size_t)rowp[e + 4] * F_IN);
        int4 v5 = *(const int4*)(xb + (size_t)rowp[e + 5] * F_IN);
        int4 v6 = *(const int4*)(xb + (size_t)rowp[e + 6] * F_IN);
        int4 v7 = *(const int4*)(xb + (size_t)rowp[e + 7] * F_IN);
        ACC4(v0); ACC4(v1); ACC4(v2); ACC4(v3);
        ACC4(v4); ACC4(v5); ACC4(v6); ACC4(v7);
    }
    for (; e + 1 < len; e += 2) {
        int4 v0 = *(const int4*)(xb + (size_t)rowp[e + 0] * F_IN);
        int4 v1 = *(const int4*)(xb + (size_t)rowp[e + 1] * F_IN);
        ACC4(v0); ACC4(v1);
    }
    if (e < len) {
        int4 v0 = *(const int4*)(xb + (size_t)rowp[e] * F_IN);
        ACC4(v0);
    }
    float dd = dinv[node];
    int4 o;
    o.x = (int)((u32)f2bf(acc[0] * dd) | ((u32)f2bf(acc[1] * dd) << 16));
    o.y = (int)((u32)f2bf(acc[2] * dd) | ((u32)f2bf(acc[3] * dd) << 16));
    o.z = (int)((u32)f2bf(acc[4] * dd) | ((u32)f2bf(acc[5] * dd) << 16));
    o.w = (int)((u32)f2bf(acc[6] * dd) | ((u32)f2bf(acc[7] * dd) << 16));
    *(int4*)(aggb + (size_t)node * H_DIM + h * 64 + q * 8) = o;
}

// ------------- GEMM1 via MFMA: hb = relu(aggb@W1 + b1) (bf16) --------------
// BN partial stats -> pstats[c][blk], plain stores.
__global__ __launch_bounds__(256) void gemm1_mfma(const u16* __restrict__ aggb,
                                                  const u16* __restrict__ W1t,
                                                  const float* __restrict__ b1,
                                                  u16* __restrict__ hb,
                                                  float* __restrict__ pstats) {
    __shared__ u16 As[G1_ROWS * G1_LD];   // 34.8 KB
    int tid = threadIdx.x;
    int base = blockIdx.x * G1_ROWS;

    {   // stage 128 node rows (256 B each), clamped at tail
        int row = tid >> 1, half = tid & 1;
        int gr = base + row; if (gr >= N_NODES) gr = N_NODES - 1;
        const int4* gsrc = (const int4*)(aggb + (size_t)gr * H_DIM + half * 64);
        int4* ldst = (int4*)(As + row * G1_LD + half * 64);
        #pragma unroll
        for (int i = 0; i < 8; ++i) ldst[i] = gsrc[i];
    }
    __syncthreads();

    int lane = tid & 63, w = tid >> 6;
    int r = lane & 15, g = lane >> 4;

    bf16x8 wf[2][4];   // [ch-tile][kstep], resident
    #pragma unroll
    for (int t = 0; t < 2; ++t)
        #pragma unroll
        for (int ks = 0; ks < 4; ++ks)
            wf[t][ks] = *(const bf16x8*)(W1t + (w * 32 + t * 16 + r) * H_DIM + ks * 32 + g * 8);

    float bch[2][4];
    #pragma unroll
    for (int t = 0; t < 2; ++t)
        #pragma unroll
        for (int i = 0; i < 4; ++i)
            bch[t][i] = b1[w * 32 + t * 16 + 4 * g + i];

    float cs[8] = {}, cq[8] = {};

    for (int rt = 0; rt < 8; ++rt) {
        f32x4 acc0 = {0.f, 0.f, 0.f, 0.f}, acc1 = {0.f, 0.f, 0.f, 0.f};
        #pragma unroll
        for (int ks = 0; ks < 4; ++ks) {
            bf16x8 nf = *(const bf16x8*)(As + (rt * 16 + r) * G1_LD + ks * 32 + g * 8);
            acc0 = __builtin_amdgcn_mfma_f32_16x16x32_bf16(wf[0][ks], nf, acc0, 0, 0, 0);
            acc1 = __builtin_amdgcn_mfma_f32_16x16x32_bf16(wf[1][ks], nf, acc1, 0, 0, 0);
        }
        int node = base + rt * 16 + r;
        if (node < N_NODES) {
            float o0[4], o1[4];
            #pragma unroll
            for (int i = 0; i < 4; ++i) {
                o0[i] = fmaxf(acc0[i] + bch[0][i], 0.f);
                o1[i] = fmaxf(acc1[i] + bch[1][i], 0.f);
                cs[i]     += o0[i]; cq[i]     += o0[i] * o0[i];
                cs[4 + i] += o1[i]; cq[4 + i] += o1[i] * o1[i];
            }
            uint2 p0, p1;
            p0.x = (u32)f2bf(o0[0]) | ((u32)f2bf(o0[1]) << 16);
            p0.y = (u32)f2bf(o0[2]) | ((u32)f2bf(o0[3]) << 16);
            p1.x = (u32)f2bf(o1[0]) | ((u32)f2bf(o1[1]) << 16);
            p1.y = (u32)f2bf(o1[2]) | ((u32)f2bf(o1[3]) << 16);
            u16* hp = hb + (size_t)node * H_DIM + w * 32 + 4 * g;
            *(uint2*)hp = p0;
            *(uint2*)(hp + 16) = p1;
        }
    }

    #pragma unroll
    for (int j = 0; j < 8; ++j) {
        #pragma unroll
        for (int m = 1; m < 16; m <<= 1) {
            cs[j] += __shfl_xor(cs[j], m, 16);
            cq[j] += __shfl_xor(cq[j], m, 16);
        }
    }
    if (r == 0) {
        #pragma unroll
        for (int j = 0; j < 8; ++j) {
            int c = w * 32 + (j >> 2) * 16 + 4 * g + (j & 3);
            pstats[c * PS_LD + blockIdx.x] = cs[j];
            pstats[(128 + c) * PS_LD + blockIdx.x] = cq[j];
        }
    }
}

// ---- reduce per-block partials -> scale/shift (one block per channel) ----
__global__ __launch_bounds__(256) void stats_final(const float* __restrict__ pstats,
                                                   const float* __restrict__ gamma,
                                                   const float* __restrict__ beta,
                                                   float* __restrict__ scale,
                                                   float* __restrict__ shift) {
    __shared__ float ls[256], lq[256];
    int c = blockIdx.x, t = threadIdx.x;
    float s = 0.f, q = 0.f;
    for (int b = t; b < G1_NB; b += 256) {
        s += pstats[c * PS_LD + b];
        q += pstats[(128 + c) * PS_LD + b];
    }
    ls[t] = s; lq[t] = q;
    __syncthreads();
    for (int off = 128; off; off >>= 1) {
        if (t < off) { ls[t] += ls[t + off]; lq[t] += lq[t + off]; }
        __syncthreads();
    }
    if (t == 0) {
        const float invn = 1.0f / (float)N_NODES;
        float mean = ls[0] * invn;
        float var = lq[0] * invn - mean * mean;
        float sc = gamma[c] * rsqrtf(var + BN_EPS);
        scale[c] = sc;
        shift[c] = beta[c] - mean * sc;
    }
}

// ---- fold BN into layer-2 weights; K[c] = sum_k shift[k]*W2[k][c] ----
__global__ __launch_bounds__(256) void w2fold(const float* __restrict__ W2,
                                              const float* __restrict__ scale,
                                              const float* __restrict__ shift,
                                              u16* __restrict__ W2t,
                                              float* __restrict__ K) {
    int t = threadIdx.x;
    for (int i = t; i < 48 * 128; i += 256) {
        int c = i >> 7, k = i & 127;
        W2t[i] = (c < C_OUT) ? f2bf(scale[k] * W2[k * C_OUT + c]) : (u16)0;
    }
    if (t < 48) {
        float a = 0.f;
        if (t < C_OUT)
            for (int k = 0; k < H_DIM; ++k) a += shift[k] * W2[k * C_OUT + t];
        K[t] = a;
    }
}

// ---- GEMM2 via MFMA: h2s[n] = bf16( dinv[n] * (hb[n]@W2t + K) )  (48 ch) ---
__global__ __launch_bounds__(256) void gemm2_mfma(const u16* __restrict__ hb,
                                                  const u16* __restrict__ W2t,
                                                  const float* __restrict__ K,
                                                  const float* __restrict__ dinv,
                                                  u16* __restrict__ h2s) {
    __shared__ u16 As[G2_ROWS * G1_LD];
    int tid = threadIdx.x;
    int base = blockIdx.x * G2_ROWS;

    {
        int row = tid >> 1, half = tid & 1;
        int gr = base + row; if (gr >= N_NODES) gr = N_NODES - 1;
        const int4* gsrc = (const int4*)(hb + (size_t)gr * H_DIM + half * 64);
        int4* ldst = (int4*)(As + row * G1_LD + half * 64);
        #pragma unroll
        for (int i = 0; i < 8; ++i) ldst[i] = gsrc[i];
    }
    __syncthreads();

    int lane = tid & 63, w = tid >> 6;
    int r = lane & 15, g = lane >> 4;

    bf16x8 wf[3][4];
    #pragma unroll
    for (int t = 0; t < 3; ++t)
        #pragma unroll
        for (int ks = 0; ks < 4; ++ks)
            wf[t][ks] = *(const bf16x8*)(W2t + (t * 16 + r) * H_DIM + ks * 32 + g * 8);

    float kv[3][4];
    #pragma unroll
    for (int t = 0; t < 3; ++t)
        #pragma unroll
        for (int i = 0; i < 4; ++i)
            kv[t][i] = K[t * 16 + 4 * g + i];

    f32x4 acc[2][3];
    #pragma unroll
    for (int i2 = 0; i2 < 2; ++i2)
        #pragma unroll
        for (int t = 0; t < 3; ++t)
            acc[i2][t] = (f32x4){0.f, 0.f, 0.f, 0.f};

    #pragma unroll
    for (int i2 = 0; i2 < 2; ++i2) {
        int rt = 2 * w + i2;
        #pragma unroll
        for (int ks = 0; ks < 4; ++ks) {
            bf16x8 nf = *(const bf16x8*)(As + (rt * 16 + r) * G1_LD + ks * 32 + g * 8);
            acc[i2][0] = __builtin_amdgcn_mfma_f32_16x16x32_bf16(wf[0][ks], nf, acc[i2][0], 0, 0, 0);
            acc[i2][1] = __builtin_amdgcn_mfma_f32_16x16x32_bf16(wf[1][ks], nf, acc[i2][1], 0, 0, 0);
            acc[i2][2] = __builtin_amdgcn_mfma_f32_16x16x32_bf16(wf[2][ks], nf, acc[i2][2], 0, 0, 0);
        }
    }

    #pragma unroll
    for (int i2 = 0; i2 < 2; ++i2) {
        int node = base + (2 * w + i2) * 16 + r;
        if (node < N_NODES) {
            float dd = dinv[node];
            u16* hp = h2s + (size_t)node * C_OUT + 4 * g;
            #pragma unroll
            for (int t = 0; t < 2; ++t) {
                uint2 p;
                p.x = (u32)f2bf((acc[i2][t][0] + kv[t][0]) * dd) |
                      ((u32)f2bf((acc[i2][t][1] + kv[t][1]) * dd) << 16);
                p.y = (u32)f2bf((acc[i2][t][2] + kv[t][2]) * dd) |
                      ((u32)f2bf((acc[i2][t][3] + kv[t][3]) * dd) << 16);
                *(uint2*)(hp + t * 16) = p;
            }
            if (g < 2) {
                uint2 p;
                p.x = (u32)f2bf((acc[i2][2][0] + kv[2][0]) * dd) |
                      ((u32)f2bf((acc[i2][2][1] + kv[2][1]) * dd) << 16);
                p.y = (u32)f2bf((acc[i2][2][2] + kv[2][2]) * dd) |
                      ((u32)f2bf((acc[i2][2][3] + kv[2][3]) * dd) << 16);
                *(uint2*)(hp + 32) = p;
            }
        }
    }
}

// --- gather layer 2: out[n] = logsoftmax(dinv[n]*sum h2s[s] + b2), 16 ln/node
__global__ __launch_bounds__(256) void gather2_fused(const int* __restrict__ cnt,
                                                     const int* __restrict__ ell,
                                                     const float* __restrict__ dinv,
                                                     const u16* __restrict__ h2s,
                                                     const float* __restrict__ b2,
                                                     float* __restrict__ out) {
    int node = blockIdx.x * 16 + (threadIdx.x >> 4);     // grid exact: N%16==0
    int q = threadIdx.x & 15;
    int len = cnt[node];
    const int* rowp = ell + (size_t)node * ELL_W;
    float a0 = 0.f, a1 = 0.f, a2 = 0.f, a3 = 0.f;
    int e = 0;
    for (; e + 7 < len; e += 8) {
        if (q < 10) {
            uint2 v0 = *(const uint2*)(h2s + (size_t)rowp[e + 0] * C_OUT + q * 4);
            uint2 v1 = *(const uint2*)(h2s + (size_t)rowp[e + 1] * C_OUT + q * 4);
            uint2 v2 = *(const uint2*)(h2s + (size_t)rowp[e + 2] * C_OUT + q * 4);
            uint2 v3 = *(const uint2*)(h2s + (size_t)rowp[e + 3] * C_OUT + q * 4);
            uint2 v4 = *(const uint2*)(h2s + (size_t)rowp[e + 4] * C_OUT + q * 4);
            uint2 v5 = *(const uint2*)(h2s + (size_t)rowp[e + 5] * C_OUT + q * 4);
            uint2 v6 = *(const uint2*)(h2s + (size_t)rowp[e + 6] * C_OUT + q * 4);
            uint2 v7 = *(const uint2*)(h2s + (size_t)rowp[e + 7] * C_OUT + q * 4);
            add2(&a0, &a1, v0.x); add2(&a2, &a3, v0.y);
            add2(&a0, &a1, v1.x); add2(&a2, &a3, v1.y);
            add2(&a0, &a1, v2.x); add2(&a2, &a3, v2.y);
            add2(&a0, &a1, v3.x); add2(&a2, &a3, v3.y);
            add2(&a0, &a1, v4.x); add2(&a2, &a3, v4.y);
            add2(&a0, &a1, v5.x); add2(&a2, &a3, v5.y);
            add2(&a0, &a1, v6.x); add2(&a2, &a3, v6.y);
            add2(&a0, &a1, v7.x); add2(&a2, &a3, v7.y);
        }
    }
    for (; e < len; ++e) {
        int s = rowp[e];
        if (q < 10) {
            uint2 v = *(const uint2*)(h2s + (size_t)s * C_OUT + q * 4);
            add2(&a0, &a1, v.x); add2(&a2, &a3, v.y);
        }
    }
    float dd = dinv[node];
    float4 r;
    float m = -INFINITY;
    if (q < 10) {
        float4 bv = *(const float4*)(b2 + q * 4);
        r.x = fmaf(a0, dd, bv.x); r.y = fmaf(a1, dd, bv.y);
        r.z = fmaf(a2, dd, bv.z); r.w = fmaf(a3, dd, bv.w);
        m = fmaxf(fmaxf(r.x, r.y), fmaxf(r.z, r.w));
    }
    #pragma unroll
    for (int off = 1; off < 16; off <<= 1) m = fmaxf(m, __shfl_xor(m, off, 16));
    float ex = 0.f;
    if (q < 10)
        ex = expf(r.x - m) + expf(r.y - m) + expf(r.z - m) + expf(r.w - m);
    #pragma unroll
    for (int off = 1; off < 16; off <<= 1) ex += __shfl_xor(ex, off, 16);
    float lse = logf(ex) + m;
    if (q < 10) {
        float4 o = {r.x - lse, r.y - lse, r.z - lse, r.w - lse};
        *(float4*)(out + (size_t)node * C_OUT + q * 4) = o;
    }
}

// ---------------- launch ----------------
extern "C" void kernel_launch(void* const* d_in, const int* in_sizes, int n_in,
                              void* d_out, int out_size, void* d_ws, size_t ws_size,
                              hipStream_t stream) {
    const float* x     = (const float*)d_in[0];
    const int*   eidx  = (const int*)d_in[1];
    const float* W1    = (const float*)d_in[2];
    const float* b1    = (const float*)d_in[3];
    const float* gamma = (const float*)d_in[4];
    const float* beta  = (const float*)d_in[5];
    const float* W2    = (const float*)d_in[6];
    const float* b2    = (const float*)d_in[7];
    float* out = (float*)d_out;

    const int* src = eidx;
    const int* dst = eidx + N_EDGES;

    // workspace layout (dword units)
    float* ws = (float*)d_ws;
    float* dinv    = ws;                        // N
    int*   cnt     = (int*)(ws + 100000);       // N
    int*   bcur    = (int*)(ws + 200000);       // NBKT*16 (+pad)
    int*   ell     = (int*)(ws + 203200);       // N*64 = 6.4M
    u16*   xs      = (u16*)(ws + 6603200);      // N*128 bf16 (6.4M dwords)
    u16*   hb      = (u16*)(ws + 6603200);      // aliases xs (xs dead after gather_x)
    u16*   aggb    = (u16*)(ws + 13003200);     // N*128 bf16; region aliases (dead before aggb)
    int2*  region  = (int2*)(ws + 13003200);    // NBKT*BKT_CAP int2 = 4.82M dwords < 6.4M
    u16*   W1t     = (u16*)(ws + 19403200);     // 128*128 bf16 = 8192 dwords
    u16*   h2s     = (u16*)(ws + 19411392);     // N*40 bf16 = 2M dwords
    float* pstats  = ws + 21411392;             // 256*800 f32
    float* scale   = ws + 21616192;             // 128
    float* shift   = ws + 21616320;             // 128
    float* K       = ws + 21616448;             // 48 (+pad)
    u16*   W2t     = (u16*)(ws + 21616512);     // 48*128 bf16 = 3072 dwords

    size_t needed = (size_t)(21616512 + 3200) * 4;   // ~86.5 MB
    if (ws_size < needed) return;

    // graph build: bucket scatter + per-bucket ELL build (no global scans)
    hipMemsetAsync(bcur, 0, NBKT * CNT_STRIDE * 4, stream);
    bucket_scatter<<<P_NB, 256, 0, stream>>>(src, dst, bcur, region);
    ell_build<<<NBKT, 256, 0, stream>>>(bcur, region, ell, cnt, dinv);

    // layer 1 (split gather: channel-halved 2-pass, 8-deep unroll)
    xconvert<<<N_NODES * F_IN / 4 / 256, 256, 0, stream>>>(x, dinv, xs);
    wconvert<<<F_IN * H_DIM / 256, 256, 0, stream>>>(W1, W1t);
    gather_x<<<dim3(N_NODES / 32, 2), 256, 0, stream>>>(cnt, ell, dinv, xs, aggb);
    gemm1_mfma<<<G1_NB, 256, 0, stream>>>(aggb, W1t, b1, hb, pstats);
    stats_final<<<128, 256, 0, stream>>>(pstats, gamma, beta, scale, shift);
    w2fold<<<1, 256, 0, stream>>>(W2, scale, shift, W2t, K);

    // layer 2
    gemm2_mfma<<<G2_NB, 256, 0, stream>>>(hb, W2t, K, dinv, h2s);
    gather2_fused<<<N_NODES / 16, 256, 0, stream>>>(cnt, ell, dinv, h2s, b2, out);
}

// Round 12
// 213.148 us; speedup vs baseline: 1.0182x; 1.0182x over previous
//
#include <hip/hip_runtime.h>
#include <math.h>

#define N_NODES 100000
#define N_EDGES 1600000
#define F_IN 128
#define H_DIM 128
#define C_OUT 40
#define BN_EPS 1e-5f

#define ELL_W 64           // slots per node; Poisson(16) => P(deg>63) ~ 1e-17
#define CNT_STRIDE 16      // bcur padding: one cursor per 64B line

#define BKT_W 512          // nodes per coarse bucket
#define NBKT ((N_NODES + BKT_W - 1) / BKT_W)            // 196
#define BKT_CAP 12288      // edges capacity per bucket (mean 8163, +45 sigma)
#define P_EDGES 2048       // edges per scatter block
#define P_NB ((N_EDGES + P_EDGES - 1) / P_EDGES)        // 782
#define FP_WCV_NB 64       // wconvert blocks
#define FP_XCV_NB 12500    // xconvert blocks (3.2M float4 / 256)

#define G1_ROWS 128
#define G1_LD 136          // shorts: 272 B row
#define G1_NB ((N_NODES + G1_ROWS - 1) / G1_ROWS)       // 782
#define PS_LD 800          // pstats stride (>= G1_NB)
#define G2_ROWS 128
#define G2_NB ((N_NODES + G2_ROWS - 1) / G2_ROWS)       // 782
#define H2_LD 64           // h2s row stride (chs): 128 B aligned rows

typedef unsigned short u16;
typedef unsigned int u32;
typedef __attribute__((ext_vector_type(8))) __bf16 bf16x8;
typedef __attribute__((ext_vector_type(4))) float f32x4;

__device__ __forceinline__ u16 f2bf(float f) {              // RNE
    u32 u = __float_as_uint(f);
    u += 0x7FFFu + ((u >> 16) & 1u);
    return (u16)(u >> 16);
}
__device__ __forceinline__ float bf2f(u16 h) {
    return __uint_as_float(((u32)h) << 16);
}
// packed dword of 2 bf16 -> two f32 adds / fmas (2 VALU each)
__device__ __forceinline__ void add2(float* a0, float* a1, u32 d) {
    *a0 += __uint_as_float(d << 16);
    *a1 += __uint_as_float(d & 0xFFFF0000u);
}
__device__ __forceinline__ void fma2(float* a0, float* a1, u32 d, float w) {
    *a0 = fmaf(__uint_as_float(d << 16), w, *a0);
    *a1 = fmaf(__uint_as_float(d & 0xFFFF0000u), w, *a1);
}
// NOTE: macro parameter must not be named 'w' (collides with .w member access)
#define FMA4(v, wt_) do { fma2(&acc[0],&acc[1],(u32)(v).x,wt_); fma2(&acc[2],&acc[3],(u32)(v).y,wt_); \
                          fma2(&acc[4],&acc[5],(u32)(v).z,wt_); fma2(&acc[6],&acc[7],(u32)(v).w,wt_); } while(0)

// ---- fused prep: [0,P_NB) bucket_scatter | [P_NB,+64) wconvert | rest xconvert
// The three sections are independent; bucket blocks dispatch first so the
// latency-bound scatter overlaps the streaming converts.
__global__ __launch_bounds__(256) void fused_prep(const float* __restrict__ x,
                                                  const float* __restrict__ W1,
                                                  const int* __restrict__ src,
                                                  const int* __restrict__ dst,
                                                  int* __restrict__ bcur,
                                                  int2* __restrict__ region,
                                                  u16* __restrict__ xb,
                                                  u16* __restrict__ W1t) {
    __shared__ int lcnt[NBKT];
    __shared__ int gofs[NBKT];
    int b = blockIdx.x, t = threadIdx.x;
    if (b < P_NB) {
        // ---- bucket_scatter ----
        for (int i = t; i < NBKT; i += 256) lcnt[i] = 0;
        __syncthreads();
        int base = b * P_EDGES;
        int d[8], bk[8];
        #pragma unroll
        for (int i = 0; i < 8; ++i) {
            int idx = base + i * 256 + t;
            if (idx < N_EDGES) {
                d[i] = dst[idx];
                bk[i] = d[i] >> 9;
                atomicAdd(&lcnt[bk[i]], 1);
            } else d[i] = -1;
        }
        __syncthreads();
        for (int i = t; i < NBKT; i += 256) {
            int c = lcnt[i];
            gofs[i] = c ? atomicAdd(&bcur[i * CNT_STRIDE], c) : 0;
            lcnt[i] = 0;                  // reuse as local rank counter
        }
        __syncthreads();
        #pragma unroll
        for (int i = 0; i < 8; ++i) {
            int idx = base + i * 256 + t;
            if (idx < N_EDGES) {
                int rank = atomicAdd(&lcnt[bk[i]], 1);
                int pos = gofs[bk[i]] + rank;
                if (pos < BKT_CAP)        // statistically impossible; guards OOB
                    region[(size_t)bk[i] * BKT_CAP + pos] = make_int2(src[idx], d[i]);
            }
        }
    } else if (b < P_NB + FP_WCV_NB) {
        // ---- wconvert: W1 [k][n] f32 -> W1t [n][k] bf16 ----
        int i = (b - P_NB) * 256 + t;     // < 16384
        int k = i >> 7, n = i & 127;
        W1t[n * H_DIM + k] = f2bf(W1[k * H_DIM + n]);
    } else {
        // ---- xconvert: xb = bf16(x), UNSCALED (no graph dependency) ----
        int i = (b - P_NB - FP_WCV_NB) * 256 + t;   // exactly 3.2M float4
        float4 v = ((const float4*)x)[i];
        ushort4 o;
        o.x = f2bf(v.x); o.y = f2bf(v.y); o.z = f2bf(v.z); o.w = f2bf(v.w);
        ((ushort4*)xb)[i] = o;
    }
}

// ---- per-bucket ELL build; scatter confined to a 128KB window ----
__global__ __launch_bounds__(256) void ell_build(const int* __restrict__ bcur,
                                                 const int2* __restrict__ region,
                                                 int* __restrict__ ell,
                                                 int* __restrict__ cnt,
                                                 float* __restrict__ dinv) {
    __shared__ int lcnt[BKT_W];
    int b = blockIdx.x, t = threadIdx.x;
    int nbase = b * BKT_W;
    for (int i = t; i < BKT_W; i += 256) {
        lcnt[i] = 1;                      // self-loop occupies slot 0
        int node = nbase + i;
        if (node < N_NODES) ell[(size_t)node * ELL_W] = node;
    }
    __syncthreads();
    int ne = bcur[b * CNT_STRIDE];
    if (ne > BKT_CAP) ne = BKT_CAP;
    const int2* reg = region + (size_t)b * BKT_CAP;
    for (int i = t; i < ne; i += 256) {
        int2 p = reg[i];
        int rank = atomicAdd(&lcnt[p.y - nbase], 1);
        if (rank < ELL_W) ell[(size_t)p.y * ELL_W + rank] = p.x;
    }
    __syncthreads();
    for (int i = t; i < BKT_W; i += 256) {
        int node = nbase + i;
        if (node < N_NODES) {
            int c = lcnt[i];
            cnt[node] = (c > ELL_W) ? ELL_W : c;
            dinv[node] = rsqrtf((float)c);   // true degree
        }
    }
}

// ------- gather layer 1: aggb[n] = bf16( dinv[n]*sum dinv[s]*xb[s] ) -------
// 16 lanes/node (8 ch each, int4 = full 256B row), 16 nodes/block, 4-unroll.
// Low VGPR for max TLP (R7 evidence: occupancy beats per-thread ILP here).
__global__ __launch_bounds__(256) void gather_x(const int* __restrict__ cnt,
                                                const int* __restrict__ ell,
                                                const float* __restrict__ dinv,
                                                const u16* __restrict__ xb,
                                                u16* __restrict__ aggb) {
    int node = blockIdx.x * 16 + (threadIdx.x >> 4);     // grid exact: N%16==0
    int q = threadIdx.x & 15;
    int len = cnt[node];
    const int* rowp = ell + (size_t)node * ELL_W;
    float acc[8] = {};
    int e = 0;
    for (; e + 3 < len; e += 4) {
        int s0 = rowp[e], s1 = rowp[e + 1], s2 = rowp[e + 2], s3 = rowp[e + 3];
        float w0 = dinv[s0], w1 = dinv[s1], w2 = dinv[s2], w3 = dinv[s3];  // broadcast, L2-hit
        int4 v0 = *(const int4*)(xb + (size_t)s0 * F_IN + q * 8);
        int4 v1 = *(const int4*)(xb + (size_t)s1 * F_IN + q * 8);
        int4 v2 = *(const int4*)(xb + (size_t)s2 * F_IN + q * 8);
        int4 v3 = *(const int4*)(xb + (size_t)s3 * F_IN + q * 8);
        FMA4(v0, w0); FMA4(v1, w1); FMA4(v2, w2); FMA4(v3, w3);
    }
    for (; e < len; ++e) {
        int s = rowp[e];
        float wv = dinv[s];
        int4 v = *(const int4*)(xb + (size_t)s * F_IN + q * 8);
        FMA4(v, wv);
    }
    float dd = dinv[node];
    int4 o;
    o.x = (int)((u32)f2bf(acc[0] * dd) | ((u32)f2bf(acc[1] * dd) << 16));
    o.y = (int)((u32)f2bf(acc[2] * dd) | ((u32)f2bf(acc[3] * dd) << 16));
    o.z = (int)((u32)f2bf(acc[4] * dd) | ((u32)f2bf(acc[5] * dd) << 16));
    o.w = (int)((u32)f2bf(acc[6] * dd) | ((u32)f2bf(acc[7] * dd) << 16));
    *(int4*)(aggb + (size_t)node * H_DIM + q * 8) = o;
}

// ------------- GEMM1 via MFMA: hb = relu(aggb@W1 + b1) (bf16) --------------
// BN partial stats -> pstats[c][blk], plain stores.
__global__ __launch_bounds__(256) void gemm1_mfma(const u16* __restrict__ aggb,
                                                  const u16* __restrict__ W1t,
                                                  const float* __restrict__ b1,
                                                  u16* __restrict__ hb,
                                                  float* __restrict__ pstats) {
    __shared__ u16 As[G1_ROWS * G1_LD];   // 34.8 KB
    int tid = threadIdx.x;
    int base = blockIdx.x * G1_ROWS;

    {   // stage 128 node rows (256 B each), clamped at tail
        int row = tid >> 1, half = tid & 1;
        int gr = base + row; if (gr >= N_NODES) gr = N_NODES - 1;
        const int4* gsrc = (const int4*)(aggb + (size_t)gr * H_DIM + half * 64);
        int4* ldst = (int4*)(As + row * G1_LD + half * 64);
        #pragma unroll
        for (int i = 0; i < 8; ++i) ldst[i] = gsrc[i];
    }
    __syncthreads();

    int lane = tid & 63, w = tid >> 6;
    int r = lane & 15, g = lane >> 4;

    bf16x8 wf[2][4];   // [ch-tile][kstep], resident
    #pragma unroll
    for (int t = 0; t < 2; ++t)
        #pragma unroll
        for (int ks = 0; ks < 4; ++ks)
            wf[t][ks] = *(const bf16x8*)(W1t + (w * 32 + t * 16 + r) * H_DIM + ks * 32 + g * 8);

    float bch[2][4];
    #pragma unroll
    for (int t = 0; t < 2; ++t)
        #pragma unroll
        for (int i = 0; i < 4; ++i)
            bch[t][i] = b1[w * 32 + t * 16 + 4 * g + i];

    float cs[8] = {}, cq[8] = {};

    for (int rt = 0; rt < 8; ++rt) {
        f32x4 acc0 = {0.f, 0.f, 0.f, 0.f}, acc1 = {0.f, 0.f, 0.f, 0.f};
        #pragma unroll
        for (int ks = 0; ks < 4; ++ks) {
            bf16x8 nf = *(const bf16x8*)(As + (rt * 16 + r) * G1_LD + ks * 32 + g * 8);
            acc0 = __builtin_amdgcn_mfma_f32_16x16x32_bf16(wf[0][ks], nf, acc0, 0, 0, 0);
            acc1 = __builtin_amdgcn_mfma_f32_16x16x32_bf16(wf[1][ks], nf, acc1, 0, 0, 0);
        }
        int node = base + rt * 16 + r;
        if (node < N_NODES) {
            float o0[4], o1[4];
            #pragma unroll
            for (int i = 0; i < 4; ++i) {
                o0[i] = fmaxf(acc0[i] + bch[0][i], 0.f);
                o1[i] = fmaxf(acc1[i] + bch[1][i], 0.f);
                cs[i]     += o0[i]; cq[i]     += o0[i] * o0[i];
                cs[4 + i] += o1[i]; cq[4 + i] += o1[i] * o1[i];
            }
            uint2 p0, p1;
            p0.x = (u32)f2bf(o0[0]) | ((u32)f2bf(o0[1]) << 16);
            p0.y = (u32)f2bf(o0[2]) | ((u32)f2bf(o0[3]) << 16);
            p1.x = (u32)f2bf(o1[0]) | ((u32)f2bf(o1[1]) << 16);
            p1.y = (u32)f2bf(o1[2]) | ((u32)f2bf(o1[3]) << 16);
            u16* hp = hb + (size_t)node * H_DIM + w * 32 + 4 * g;
            *(uint2*)hp = p0;
            *(uint2*)(hp + 16) = p1;
        }
    }

    #pragma unroll
    for (int j = 0; j < 8; ++j) {
        #pragma unroll
        for (int m = 1; m < 16; m <<= 1) {
            cs[j] += __shfl_xor(cs[j], m, 16);
            cq[j] += __shfl_xor(cq[j], m, 16);
        }
    }
    if (r == 0) {
        #pragma unroll
        for (int j = 0; j < 8; ++j) {
            int c = w * 32 + (j >> 2) * 16 + 4 * g + (j & 3);
            pstats[c * PS_LD + blockIdx.x] = cs[j];
            pstats[(128 + c) * PS_LD + blockIdx.x] = cq[j];
        }
    }
}

// ---- reduce per-block partials -> scale/shift (one block per channel) ----
__global__ __launch_bounds__(256) void stats_final(const float* __restrict__ pstats,
                                                   const float* __restrict__ gamma,
                                                   const float* __restrict__ beta,
                                                   float* __restrict__ scale,
                                                   float* __restrict__ shift) {
    __shared__ float ls[256], lq[256];
    int c = blockIdx.x, t = threadIdx.x;
    float s = 0.f, q = 0.f;
    for (int b = t; b < G1_NB; b += 256) {
        s += pstats[c * PS_LD + b];
        q += pstats[(128 + c) * PS_LD + b];
    }
    ls[t] = s; lq[t] = q;
    __syncthreads();
    for (int off = 128; off; off >>= 1) {
        if (t < off) { ls[t] += ls[t + off]; lq[t] += lq[t + off]; }
        __syncthreads();
    }
    if (t == 0) {
        const float invn = 1.0f / (float)N_NODES;
        float mean = ls[0] * invn;
        float var = lq[0] * invn - mean * mean;
        float sc = gamma[c] * rsqrtf(var + BN_EPS);
        scale[c] = sc;
        shift[c] = beta[c] - mean * sc;
    }
}

// ---- fold BN into layer-2 weights; K[c] = sum_k shift[k]*W2[k][c] ----
__global__ __launch_bounds__(256) void w2fold(const float* __restrict__ W2,
                                              const float* __restrict__ scale,
                                              const float* __restrict__ shift,
                                              u16* __restrict__ W2t,
                                              float* __restrict__ K) {
    int t = threadIdx.x;
    for (int i = t; i < 48 * 128; i += 256) {
        int c = i >> 7, k = i & 127;
        W2t[i] = (c < C_OUT) ? f2bf(scale[k] * W2[k * C_OUT + c]) : (u16)0;
    }
    if (t < 48) {
        float a = 0.f;
        if (t < C_OUT)
            for (int k = 0; k < H_DIM; ++k) a += shift[k] * W2[k * C_OUT + t];
        K[t] = a;
    }
}

// ---- GEMM2 via MFMA: h2s[n] = bf16( dinv[n] * (hb[n]@W2t + K) ),
// stored at 64-ch stride (128 B aligned rows for gather2) ----
__global__ __launch_bounds__(256) void gemm2_mfma(const u16* __restrict__ hb,
                                                  const u16* __restrict__ W2t,
                                                  const float* __restrict__ K,
                                                  const float* __restrict__ dinv,
                                                  u16* __restrict__ h2s) {
    __shared__ u16 As[G2_ROWS * G1_LD];
    int tid = threadIdx.x;
    int base = blockIdx.x * G2_ROWS;

    {
        int row = tid >> 1, half = tid & 1;
        int gr = base + row; if (gr >= N_NODES) gr = N_NODES - 1;
        const int4* gsrc = (const int4*)(hb + (size_t)gr * H_DIM + half * 64);
        int4* ldst = (int4*)(As + row * G1_LD + half * 64);
        #pragma unroll
        for (int i = 0; i < 8; ++i) ldst[i] = gsrc[i];
    }
    __syncthreads();

    int lane = tid & 63, w = tid >> 6;
    int r = lane & 15, g = lane >> 4;

    bf16x8 wf[3][4];
    #pragma unroll
    for (int t = 0; t < 3; ++t)
        #pragma unroll
        for (int ks = 0; ks < 4; ++ks)
            wf[t][ks] = *(const bf16x8*)(W2t + (t * 16 + r) * H_DIM + ks * 32 + g * 8);

    float kv[3][4];
    #pragma unroll
    for (int t = 0; t < 3; ++t)
        #pragma unroll
        for (int i = 0; i < 4; ++i)
            kv[t][i] = K[t * 16 + 4 * g + i];

    f32x4 acc[2][3];
    #pragma unroll
    for (int i2 = 0; i2 < 2; ++i2)
        #pragma unroll
        for (int t = 0; t < 3; ++t)
            acc[i2][t] = (f32x4){0.f, 0.f, 0.f, 0.f};

    #pragma unroll
    for (int i2 = 0; i2 < 2; ++i2) {
        int rt = 2 * w + i2;
        #pragma unroll
        for (int ks = 0; ks < 4; ++ks) {
            bf16x8 nf = *(const bf16x8*)(As + (rt * 16 + r) * G1_LD + ks * 32 + g * 8);
            acc[i2][0] = __builtin_amdgcn_mfma_f32_16x16x32_bf16(wf[0][ks], nf, acc[i2][0], 0, 0, 0);
            acc[i2][1] = __builtin_amdgcn_mfma_f32_16x16x32_bf16(wf[1][ks], nf, acc[i2][1], 0, 0, 0);
            acc[i2][2] = __builtin_amdgcn_mfma_f32_16x16x32_bf16(wf[2][ks], nf, acc[i2][2], 0, 0, 0);
        }
    }

    #pragma unroll
    for (int i2 = 0; i2 < 2; ++i2) {
        int node = base + (2 * w + i2) * 16 + r;
        if (node < N_NODES) {
            float dd = dinv[node];
            u16* hp = h2s + (size_t)node * H2_LD + 4 * g;
            #pragma unroll
            for (int t = 0; t < 2; ++t) {
                uint2 p;
                p.x = (u32)f2bf((acc[i2][t][0] + kv[t][0]) * dd) |
                      ((u32)f2bf((acc[i2][t][1] + kv[t][1]) * dd) << 16);
                p.y = (u32)f2bf((acc[i2][t][2] + kv[t][2]) * dd) |
                      ((u32)f2bf((acc[i2][t][3] + kv[t][3]) * dd) << 16);
                *(uint2*)(hp + t * 16) = p;
            }
            if (g < 2) {
                uint2 p;
                p.x = (u32)f2bf((acc[i2][2][0] + kv[2][0]) * dd) |
                      ((u32)f2bf((acc[i2][2][1] + kv[2][1]) * dd) << 16);
                p.y = (u32)f2bf((acc[i2][2][2] + kv[2][2]) * dd) |
                      ((u32)f2bf((acc[i2][2][3] + kv[2][3]) * dd) << 16);
                *(uint2*)(hp + 32) = p;
            }
        }
    }
}

// --- gather layer 2: out[n] = logsoftmax(dinv[n]*sum h2s[s] + b2), 16 ln/node
__global__ __launch_bounds__(256) void gather2_fused(const int* __restrict__ cnt,
                                                     const int* __restrict__ ell,
                                                     const float* __restrict__ dinv,
                                                     const u16* __restrict__ h2s,
                                                     const float* __restrict__ b2,
                                                     float* __restrict__ out) {
    int node = blockIdx.x * 16 + (threadIdx.x >> 4);     // grid exact: N%16==0
    int q = threadIdx.x & 15;
    int len = cnt[node];
    const int* rowp = ell + (size_t)node * ELL_W;
    float a0 = 0.f, a1 = 0.f, a2 = 0.f, a3 = 0.f;
    int e = 0;
    for (; e + 7 < len; e += 8) {
        if (q < 10) {
            uint2 v0 = *(const uint2*)(h2s + (size_t)rowp[e + 0] * H2_LD + q * 4);
            uint2 v1 = *(const uint2*)(h2s + (size_t)rowp[e + 1] * H2_LD + q * 4);
            uint2 v2 = *(const uint2*)(h2s + (size_t)rowp[e + 2] * H2_LD + q * 4);
            uint2 v3 = *(const uint2*)(h2s + (size_t)rowp[e + 3] * H2_LD + q * 4);
            uint2 v4 = *(const uint2*)(h2s + (size_t)rowp[e + 4] * H2_LD + q * 4);
            uint2 v5 = *(const uint2*)(h2s + (size_t)rowp[e + 5] * H2_LD + q * 4);
            uint2 v6 = *(const uint2*)(h2s + (size_t)rowp[e + 6] * H2_LD + q * 4);
            uint2 v7 = *(const uint2*)(h2s + (size_t)rowp[e + 7] * H2_LD + q * 4);
            add2(&a0, &a1, v0.x); add2(&a2, &a3, v0.y);
            add2(&a0, &a1, v1.x); add2(&a2, &a3, v1.y);
            add2(&a0, &a1, v2.x); add2(&a2, &a3, v2.y);
            add2(&a0, &a1, v3.x); add2(&a2, &a3, v3.y);
            add2(&a0, &a1, v4.x); add2(&a2, &a3, v4.y);
            add2(&a0, &a1, v5.x); add2(&a2, &a3, v5.y);
            add2(&a0, &a1, v6.x); add2(&a2, &a3, v6.y);
            add2(&a0, &a1, v7.x); add2(&a2, &a3, v7.y);
        }
    }
    for (; e < len; ++e) {
        int s = rowp[e];
        if (q < 10) {
            uint2 v = *(const uint2*)(h2s + (size_t)s * H2_LD + q * 4);
            add2(&a0, &a1, v.x); add2(&a2, &a3, v.y);
        }
    }
    float dd = dinv[node];
    float4 r;
    float m = -INFINITY;
    if (q < 10) {
        float4 bv = *(const float4*)(b2 + q * 4);
        r.x = fmaf(a0, dd, bv.x); r.y = fmaf(a1, dd, bv.y);
        r.z = fmaf(a2, dd, bv.z); r.w = fmaf(a3, dd, bv.w);
        m = fmaxf(fmaxf(r.x, r.y), fmaxf(r.z, r.w));
    }
    #pragma unroll
    for (int off = 1; off < 16; off <<= 1) m = fmaxf(m, __shfl_xor(m, off, 16));
    float ex = 0.f;
    if (q < 10)
        ex = expf(r.x - m) + expf(r.y - m) + expf(r.z - m) + expf(r.w - m);
    #pragma unroll
    for (int off = 1; off < 16; off <<= 1) ex += __shfl_xor(ex, off, 16);
    float lse = logf(ex) + m;
    if (q < 10) {
        float4 o = {r.x - lse, r.y - lse, r.z - lse, r.w - lse};
        *(float4*)(out + (size_t)node * C_OUT + q * 4) = o;
    }
}

// ---------------- launch ----------------
extern "C" void kernel_launch(void* const* d_in, const int* in_sizes, int n_in,
                              void* d_out, int out_size, void* d_ws, size_t ws_size,
                              hipStream_t stream) {
    const float* x     = (const float*)d_in[0];
    const int*   eidx  = (const int*)d_in[1];
    const float* W1    = (const float*)d_in[2];
    const float* b1    = (const float*)d_in[3];
    const float* gamma = (const float*)d_in[4];
    const float* beta  = (const float*)d_in[5];
    const float* W2    = (const float*)d_in[6];
    const float* b2    = (const float*)d_in[7];
    float* out = (float*)d_out;

    const int* src = eidx;
    const int* dst = eidx + N_EDGES;

    // workspace layout (dword units)
    float* ws = (float*)d_ws;
    float* dinv    = ws;                        // N
    int*   cnt     = (int*)(ws + 100000);       // N
    int*   bcur    = (int*)(ws + 200000);       // NBKT*16 (+pad)
    int*   ell     = (int*)(ws + 203200);       // N*64 = 6.4M
    u16*   xb      = (u16*)(ws + 6603200);      // N*128 bf16 (6.4M dwords)
    u16*   hb      = (u16*)(ws + 6603200);      // aliases xb (xb dead after gather_x)
    u16*   aggb    = (u16*)(ws + 13003200);     // N*128 bf16; region aliases (dead before aggb)
    int2*  region  = (int2*)(ws + 13003200);    // NBKT*BKT_CAP int2 = 4.82M dwords < 6.4M
    u16*   W1t     = (u16*)(ws + 19403200);     // 128*128 bf16 = 8192 dwords
    u16*   h2s     = (u16*)(ws + 19411392);     // N*64 bf16 = 3.2M dwords (128B rows)
    float* pstats  = ws + 22611392;             // 256*800 f32 = 204800
    float* scale   = ws + 22816192;             // 128
    float* shift   = ws + 22816320;             // 128
    float* K       = ws + 22816448;             // 48 (+pad to 64)
    u16*   W2t     = (u16*)(ws + 22816512);     // 48*128 bf16 = 3072 dwords

    size_t needed = (size_t)(22816512 + 3072 + 256) * 4;   // ~91.3 MB (< 99.2 proven)
    if (ws_size < needed) return;

    // prep: converts overlap the bucket scatter in one kernel
    hipMemsetAsync(bcur, 0, NBKT * CNT_STRIDE * 4, stream);
    fused_prep<<<P_NB + FP_WCV_NB + FP_XCV_NB, 256, 0, stream>>>(
        x, W1, src, dst, bcur, region, xb, W1t);
    ell_build<<<NBKT, 256, 0, stream>>>(bcur, region, ell, cnt, dinv);

    // layer 1
    gather_x<<<N_NODES / 16, 256, 0, stream>>>(cnt, ell, dinv, xb, aggb);
    gemm1_mfma<<<G1_NB, 256, 0, stream>>>(aggb, W1t, b1, hb, pstats);
    stats_final<<<128, 256, 0, stream>>>(pstats, gamma, beta, scale, shift);
    w2fold<<<1, 256, 0, stream>>>(W2, scale, shift, W2t, K);

    // layer 2
    gemm2_mfma<<<G2_NB, 256, 0, stream>>>(hb, W2t, K, dinv, h2s);
    gather2_fused<<<N_NODES / 16, 256, 0, stream>>>(cnt, ell, dinv, h2s, b2, out);
}

// Round 13
// 174.577 us; speedup vs baseline: 1.2432x; 1.2209x over previous
//
#include <hip/hip_runtime.h>
#include <math.h>

#define N_NODES 100000
#define N_EDGES 1600000
#define F_IN 128
#define H_DIM 128
#define C_OUT 40
#define BN_EPS 1e-5f

#define ELL_W 64           // slots per node; Poisson(16) => P(deg>63) ~ 1e-17
#define CNT_STRIDE 16      // bcur padding: one cursor per 64B line

#define BKT_W 512          // nodes per coarse bucket
#define NBKT ((N_NODES + BKT_W - 1) / BKT_W)            // 196
#define BKT_CAP 12288      // edges capacity per bucket (mean 8163, +45 sigma)
#define P_EDGES 2048       // edges per scatter block
#define P_NB ((N_EDGES + P_EDGES - 1) / P_EDGES)        // 782
#define FP_WCV_NB 64       // wconvert blocks
#define FP_XQ_NB 6250      // x-quantize blocks (16 rows/block)

#define G1_ROWS 128
#define G1_LD 136          // shorts: 272 B row
#define G1_NB ((N_NODES + G1_ROWS - 1) / G1_ROWS)       // 782
#define PS_LD 800          // pstats stride (>= G1_NB)
#define G2_ROWS 128
#define G2_NB ((N_NODES + G2_ROWS - 1) / G2_ROWS)       // 782
#define H2_B 64            // h2q row bytes (40 int8 + 24 zero pad = 1 line)

typedef unsigned short u16;
typedef unsigned int u32;
typedef signed char s8;
typedef __attribute__((ext_vector_type(8))) __bf16 bf16x8;
typedef __attribute__((ext_vector_type(4))) float f32x4;

__device__ __forceinline__ u16 f2bf(float f) {              // RNE
    u32 u = __float_as_uint(f);
    u += 0x7FFFu + ((u >> 16) & 1u);
    return (u16)(u >> 16);
}
// 4 packed int8 -> 4 f32 fma (bfe + cvt + fma each)
__device__ __forceinline__ void qfma4(float* a, u32 d, float w) {
    a[0] = fmaf((float)((int)(d << 24) >> 24), w, a[0]);
    a[1] = fmaf((float)((int)(d << 16) >> 24), w, a[1]);
    a[2] = fmaf((float)((int)(d <<  8) >> 24), w, a[2]);
    a[3] = fmaf((float)((int)d >> 24),         w, a[3]);
}
__device__ __forceinline__ u32 pack4(int q0, int q1, int q2, int q3) {
    return (u32)(q0 & 255) | ((u32)(q1 & 255) << 8) |
           ((u32)(q2 & 255) << 16) | ((u32)(q3 & 255) << 24);
}

// ---- fused prep: [0,P_NB) bucket_scatter | [+64) wconvert | rest x int8-quant
__global__ __launch_bounds__(256) void fused_prep(const float* __restrict__ x,
                                                  const float* __restrict__ W1,
                                                  const int* __restrict__ src,
                                                  const int* __restrict__ dst,
                                                  int* __restrict__ bcur,
                                                  int2* __restrict__ region,
                                                  s8* __restrict__ xq,
                                                  float* __restrict__ qs1,
                                                  u16* __restrict__ W1t) {
    __shared__ int lcnt[NBKT];
    __shared__ int gofs[NBKT];
    int b = blockIdx.x, t = threadIdx.x;
    if (b < P_NB) {
        // ---- bucket_scatter ----
        for (int i = t; i < NBKT; i += 256) lcnt[i] = 0;
        __syncthreads();
        int base = b * P_EDGES;
        int d[8], bk[8];
        #pragma unroll
        for (int i = 0; i < 8; ++i) {
            int idx = base + i * 256 + t;
            if (idx < N_EDGES) {
                d[i] = dst[idx];
                bk[i] = d[i] >> 9;
                atomicAdd(&lcnt[bk[i]], 1);
            } else d[i] = -1;
        }
        __syncthreads();
        for (int i = t; i < NBKT; i += 256) {
            int c = lcnt[i];
            gofs[i] = c ? atomicAdd(&bcur[i * CNT_STRIDE], c) : 0;
            lcnt[i] = 0;                  // reuse as local rank counter
        }
        __syncthreads();
        #pragma unroll
        for (int i = 0; i < 8; ++i) {
            int idx = base + i * 256 + t;
            if (idx < N_EDGES) {
                int rank = atomicAdd(&lcnt[bk[i]], 1);
                int pos = gofs[bk[i]] + rank;
                if (pos < BKT_CAP)        // statistically impossible; guards OOB
                    region[(size_t)bk[i] * BKT_CAP + pos] = make_int2(src[idx], d[i]);
            }
        }
    } else if (b < P_NB + FP_WCV_NB) {
        // ---- wconvert: W1 [k][n] f32 -> W1t [n][k] bf16 ----
        int i = (b - P_NB) * 256 + t;     // < 16384
        int k = i >> 7, n = i & 127;
        W1t[n * H_DIM + k] = f2bf(W1[k * H_DIM + n]);
    } else {
        // ---- x int8 quantize, per-row scale: 16 lanes/row, 16 rows/block ----
        int row = (b - P_NB - FP_WCV_NB) * 16 + (t >> 4);   // < 100000 exactly
        int lane = t & 15;
        const float4* xr = (const float4*)(x + (size_t)row * F_IN + lane * 8);
        float4 a = xr[0], c = xr[1];
        float m = fmaxf(fmaxf(fmaxf(fabsf(a.x), fabsf(a.y)), fmaxf(fabsf(a.z), fabsf(a.w))),
                        fmaxf(fmaxf(fabsf(c.x), fabsf(c.y)), fmaxf(fabsf(c.z), fabsf(c.w))));
        #pragma unroll
        for (int off = 1; off < 16; off <<= 1) m = fmaxf(m, __shfl_xor(m, off, 16));
        m = fmaxf(m, 1e-20f);
        float inv = 127.f / m;
        u32 p0 = pack4((int)rintf(a.x * inv), (int)rintf(a.y * inv),
                       (int)rintf(a.z * inv), (int)rintf(a.w * inv));
        u32 p1 = pack4((int)rintf(c.x * inv), (int)rintf(c.y * inv),
                       (int)rintf(c.z * inv), (int)rintf(c.w * inv));
        uint2 p; p.x = p0; p.y = p1;
        *(uint2*)(xq + (size_t)row * F_IN + lane * 8) = p;
        if (lane == 0) qs1[row] = m / 127.f;     // s_row; dinv folded in ell_build
    }
}

// ---- per-bucket ELL build; scatter confined to a 128KB window ----
// Also finalizes dinv and qscale1 (= s_row * dinv) in place.
__global__ __launch_bounds__(256) void ell_build(const int* __restrict__ bcur,
                                                 const int2* __restrict__ region,
                                                 int* __restrict__ ell,
                                                 int* __restrict__ cnt,
                                                 float* __restrict__ dinv,
                                                 float* __restrict__ qs1) {
    __shared__ int lcnt[BKT_W];
    int b = blockIdx.x, t = threadIdx.x;
    int nbase = b * BKT_W;
    for (int i = t; i < BKT_W; i += 256) {
        lcnt[i] = 1;                      // self-loop occupies slot 0
        int node = nbase + i;
        if (node < N_NODES) ell[(size_t)node * ELL_W] = node;
    }
    __syncthreads();
    int ne = bcur[b * CNT_STRIDE];
    if (ne > BKT_CAP) ne = BKT_CAP;
    const int2* reg = region + (size_t)b * BKT_CAP;
    for (int i = t; i < ne; i += 256) {
        int2 p = reg[i];
        int rank = atomicAdd(&lcnt[p.y - nbase], 1);
        if (rank < ELL_W) ell[(size_t)p.y * ELL_W + rank] = p.x;
    }
    __syncthreads();
    for (int i = t; i < BKT_W; i += 256) {
        int node = nbase + i;
        if (node < N_NODES) {
            int c = lcnt[i];
            cnt[node] = (c > ELL_W) ? ELL_W : c;
            float dv = rsqrtf((float)c);   // true degree
            dinv[node] = dv;
            qs1[node] *= dv;               // qscale1 = s_row * dinv  (in place)
        }
    }
}

// ------- gather layer 1 (int8): aggb[n] = bf16( dinv[n]*sum qs1[s]*xq[s] ) --
// 16 lanes/node (8 ch each, uint2 = 8 B), 16 nodes/block, 4-edge unroll.
__global__ __launch_bounds__(256) void gather_x(const int* __restrict__ cnt,
                                                const int* __restrict__ ell,
                                                const float* __restrict__ dinv,
                                                const float* __restrict__ qs1,
                                                const s8* __restrict__ xq,
                                                u16* __restrict__ aggb) {
    int node = blockIdx.x * 16 + (threadIdx.x >> 4);     // grid exact: N%16==0
    int q = threadIdx.x & 15;
    int len = cnt[node];
    const int* rowp = ell + (size_t)node * ELL_W;
    float acc[8] = {};
    int e = 0;
    for (; e + 3 < len; e += 4) {
        int s0 = rowp[e], s1 = rowp[e + 1], s2 = rowp[e + 2], s3 = rowp[e + 3];
        float w0 = qs1[s0], w1 = qs1[s1], w2 = qs1[s2], w3 = qs1[s3];
        uint2 v0 = *(const uint2*)(xq + (size_t)s0 * F_IN + q * 8);
        uint2 v1 = *(const uint2*)(xq + (size_t)s1 * F_IN + q * 8);
        uint2 v2 = *(const uint2*)(xq + (size_t)s2 * F_IN + q * 8);
        uint2 v3 = *(const uint2*)(xq + (size_t)s3 * F_IN + q * 8);
        qfma4(acc, v0.x, w0); qfma4(acc + 4, v0.y, w0);
        qfma4(acc, v1.x, w1); qfma4(acc + 4, v1.y, w1);
        qfma4(acc, v2.x, w2); qfma4(acc + 4, v2.y, w2);
        qfma4(acc, v3.x, w3); qfma4(acc + 4, v3.y, w3);
    }
    for (; e < len; ++e) {
        int s = rowp[e];
        float wv = qs1[s];
        uint2 v = *(const uint2*)(xq + (size_t)s * F_IN + q * 8);
        qfma4(acc, v.x, wv); qfma4(acc + 4, v.y, wv);
    }
    float dd = dinv[node];
    int4 o;
    o.x = (int)((u32)f2bf(acc[0] * dd) | ((u32)f2bf(acc[1] * dd) << 16));
    o.y = (int)((u32)f2bf(acc[2] * dd) | ((u32)f2bf(acc[3] * dd) << 16));
    o.z = (int)((u32)f2bf(acc[4] * dd) | ((u32)f2bf(acc[5] * dd) << 16));
    o.w = (int)((u32)f2bf(acc[6] * dd) | ((u32)f2bf(acc[7] * dd) << 16));
    *(int4*)(aggb + (size_t)node * H_DIM + q * 8) = o;
}

// ------------- GEMM1 via MFMA: hb = relu(aggb@W1 + b1) (bf16) --------------
__global__ __launch_bounds__(256) void gemm1_mfma(const u16* __restrict__ aggb,
                                                  const u16* __restrict__ W1t,
                                                  const float* __restrict__ b1,
                                                  u16* __restrict__ hb,
                                                  float* __restrict__ pstats) {
    __shared__ u16 As[G1_ROWS * G1_LD];   // 34.8 KB
    int tid = threadIdx.x;
    int base = blockIdx.x * G1_ROWS;

    {   // stage 128 node rows (256 B each), clamped at tail
        int row = tid >> 1, half = tid & 1;
        int gr = base + row; if (gr >= N_NODES) gr = N_NODES - 1;
        const int4* gsrc = (const int4*)(aggb + (size_t)gr * H_DIM + half * 64);
        int4* ldst = (int4*)(As + row * G1_LD + half * 64);
        #pragma unroll
        for (int i = 0; i < 8; ++i) ldst[i] = gsrc[i];
    }
    __syncthreads();

    int lane = tid & 63, w = tid >> 6;
    int r = lane & 15, g = lane >> 4;

    bf16x8 wf[2][4];   // [ch-tile][kstep], resident
    #pragma unroll
    for (int t = 0; t < 2; ++t)
        #pragma unroll
        for (int ks = 0; ks < 4; ++ks)
            wf[t][ks] = *(const bf16x8*)(W1t + (w * 32 + t * 16 + r) * H_DIM + ks * 32 + g * 8);

    float bch[2][4];
    #pragma unroll
    for (int t = 0; t < 2; ++t)
        #pragma unroll
        for (int i = 0; i < 4; ++i)
            bch[t][i] = b1[w * 32 + t * 16 + 4 * g + i];

    float cs[8] = {}, cq[8] = {};

    for (int rt = 0; rt < 8; ++rt) {
        f32x4 acc0 = {0.f, 0.f, 0.f, 0.f}, acc1 = {0.f, 0.f, 0.f, 0.f};
        #pragma unroll
        for (int ks = 0; ks < 4; ++ks) {
            bf16x8 nf = *(const bf16x8*)(As + (rt * 16 + r) * G1_LD + ks * 32 + g * 8);
            acc0 = __builtin_amdgcn_mfma_f32_16x16x32_bf16(wf[0][ks], nf, acc0, 0, 0, 0);
            acc1 = __builtin_amdgcn_mfma_f32_16x16x32_bf16(wf[1][ks], nf, acc1, 0, 0, 0);
        }
        int node = base + rt * 16 + r;
        if (node < N_NODES) {
            float o0[4], o1[4];
            #pragma unroll
            for (int i = 0; i < 4; ++i) {
                o0[i] = fmaxf(acc0[i] + bch[0][i], 0.f);
                o1[i] = fmaxf(acc1[i] + bch[1][i], 0.f);
                cs[i]     += o0[i]; cq[i]     += o0[i] * o0[i];
                cs[4 + i] += o1[i]; cq[4 + i] += o1[i] * o1[i];
            }
            uint2 p0, p1;
            p0.x = (u32)f2bf(o0[0]) | ((u32)f2bf(o0[1]) << 16);
            p0.y = (u32)f2bf(o0[2]) | ((u32)f2bf(o0[3]) << 16);
            p1.x = (u32)f2bf(o1[0]) | ((u32)f2bf(o1[1]) << 16);
            p1.y = (u32)f2bf(o1[2]) | ((u32)f2bf(o1[3]) << 16);
            u16* hp = hb + (size_t)node * H_DIM + w * 32 + 4 * g;
            *(uint2*)hp = p0;
            *(uint2*)(hp + 16) = p1;
        }
    }

    #pragma unroll
    for (int j = 0; j < 8; ++j) {
        #pragma unroll
        for (int m = 1; m < 16; m <<= 1) {
            cs[j] += __shfl_xor(cs[j], m, 16);
            cq[j] += __shfl_xor(cq[j], m, 16);
        }
    }
    if (r == 0) {
        #pragma unroll
        for (int j = 0; j < 8; ++j) {
            int c = w * 32 + (j >> 2) * 16 + 4 * g + (j & 3);
            pstats[c * PS_LD + blockIdx.x] = cs[j];
            pstats[(128 + c) * PS_LD + blockIdx.x] = cq[j];
        }
    }
}

// ---- reduce per-block partials -> scale/shift (one block per channel) ----
__global__ __launch_bounds__(256) void stats_final(const float* __restrict__ pstats,
                                                   const float* __restrict__ gamma,
                                                   const float* __restrict__ beta,
                                                   float* __restrict__ scale,
                                                   float* __restrict__ shift) {
    __shared__ float ls[256], lq[256];
    int c = blockIdx.x, t = threadIdx.x;
    float s = 0.f, q = 0.f;
    for (int b = t; b < G1_NB; b += 256) {
        s += pstats[c * PS_LD + b];
        q += pstats[(128 + c) * PS_LD + b];
    }
    ls[t] = s; lq[t] = q;
    __syncthreads();
    for (int off = 128; off; off >>= 1) {
        if (t < off) { ls[t] += ls[t + off]; lq[t] += lq[t + off]; }
        __syncthreads();
    }
    if (t == 0) {
        const float invn = 1.0f / (float)N_NODES;
        float mean = ls[0] * invn;
        float var = lq[0] * invn - mean * mean;
        float sc = gamma[c] * rsqrtf(var + BN_EPS);
        scale[c] = sc;
        shift[c] = beta[c] - mean * sc;
    }
}

// ---- fold BN into layer-2 weights; one block per padded channel c<48 ----
__global__ __launch_bounds__(128) void w2fold(const float* __restrict__ W2,
                                              const float* __restrict__ scale,
                                              const float* __restrict__ shift,
                                              u16* __restrict__ W2t,
                                              float* __restrict__ K) {
    __shared__ float red[128];
    int c = blockIdx.x, k = threadIdx.x;
    float wv = (c < C_OUT) ? W2[k * C_OUT + c] : 0.f;
    W2t[c * H_DIM + k] = (c < C_OUT) ? f2bf(scale[k] * wv) : (u16)0;
    red[k] = shift[k] * wv;
    __syncthreads();
    for (int off = 64; off; off >>= 1) {
        if (k < off) red[k] += red[k + off];
        __syncthreads();
    }
    if (k == 0) K[c] = red[0];
}

// ---- GEMM2 via MFMA -> int8 row-quantized h2q (64 B rows incl. zero pad) ---
__global__ __launch_bounds__(256) void gemm2_mfma(const u16* __restrict__ hb,
                                                  const u16* __restrict__ W2t,
                                                  const float* __restrict__ K,
                                                  const float* __restrict__ dinv,
                                                  s8* __restrict__ h2q,
                                                  float* __restrict__ srow2) {
    __shared__ u16 As[G2_ROWS * G1_LD];
    int tid = threadIdx.x;
    int base = blockIdx.x * G2_ROWS;

    {
        int row = tid >> 1, half = tid & 1;
        int gr = base + row; if (gr >= N_NODES) gr = N_NODES - 1;
        const int4* gsrc = (const int4*)(hb + (size_t)gr * H_DIM + half * 64);
        int4* ldst = (int4*)(As + row * G1_LD + half * 64);
        #pragma unroll
        for (int i = 0; i < 8; ++i) ldst[i] = gsrc[i];
    }
    __syncthreads();

    int lane = tid & 63, w = tid >> 6;
    int r = lane & 15, g = lane >> 4;

    bf16x8 wf[3][4];
    #pragma unroll
    for (int t = 0; t < 3; ++t)
        #pragma unroll
        for (int ks = 0; ks < 4; ++ks)
            wf[t][ks] = *(const bf16x8*)(W2t + (t * 16 + r) * H_DIM + ks * 32 + g * 8);

    float kv[3][4];
    #pragma unroll
    for (int t = 0; t < 3; ++t)
        #pragma unroll
        for (int i = 0; i < 4; ++i)
            kv[t][i] = K[t * 16 + 4 * g + i];

    f32x4 acc[2][3];
    #pragma unroll
    for (int i2 = 0; i2 < 2; ++i2)
        #pragma unroll
        for (int t = 0; t < 3; ++t)
            acc[i2][t] = (f32x4){0.f, 0.f, 0.f, 0.f};

    #pragma unroll
    for (int i2 = 0; i2 < 2; ++i2) {
        int rt = 2 * w + i2;
        #pragma unroll
        for (int ks = 0; ks < 4; ++ks) {
            bf16x8 nf = *(const bf16x8*)(As + (rt * 16 + r) * G1_LD + ks * 32 + g * 8);
            acc[i2][0] = __builtin_amdgcn_mfma_f32_16x16x32_bf16(wf[0][ks], nf, acc[i2][0], 0, 0, 0);
            acc[i2][1] = __builtin_amdgcn_mfma_f32_16x16x32_bf16(wf[1][ks], nf, acc[i2][1], 0, 0, 0);
            acc[i2][2] = __builtin_amdgcn_mfma_f32_16x16x32_bf16(wf[2][ks], nf, acc[i2][2], 0, 0, 0);
        }
    }

    #pragma unroll
    for (int i2 = 0; i2 < 2; ++i2) {
        int node = base + (2 * w + i2) * 16 + r;
        float dd = (node < N_NODES) ? dinv[node] : 0.f;
        float v[3][4];
        float m = 0.f;
        #pragma unroll
        for (int t = 0; t < 3; ++t)
            #pragma unroll
            for (int i = 0; i < 4; ++i) {
                v[t][i] = (acc[i2][t][i] + kv[t][i]) * dd;
                if (t < 2 || g < 2) m = fmaxf(m, fabsf(v[t][i]));
            }
        m = fmaxf(m, __shfl_xor(m, 16));     // across g pairs
        m = fmaxf(m, __shfl_xor(m, 32));
        m = fmaxf(m, 1e-20f);
        float inv = 127.f / m;
        if (node < N_NODES) {
            s8* hp = h2q + (size_t)node * H2_B;
            #pragma unroll
            for (int t = 0; t < 2; ++t) {
                u32 p = pack4((int)rintf(v[t][0] * inv), (int)rintf(v[t][1] * inv),
                              (int)rintf(v[t][2] * inv), (int)rintf(v[t][3] * inv));
                *(u32*)(hp + t * 16 + 4 * g) = p;
            }
            u32 p2 = (g < 2) ? pack4((int)rintf(v[2][0] * inv), (int)rintf(v[2][1] * inv),
                                     (int)rintf(v[2][2] * inv), (int)rintf(v[2][3] * inv))
                             : 0u;
            *(u32*)(hp + 32 + 4 * g) = p2;       // g>=2 zeroes ch 40-47
            *(u32*)(hp + 48 + 4 * g) = 0u;       // ch 48-63 zero
            if (g == 0) srow2[node] = m / 127.f;
        }
    }
}

// --- gather layer 2 (int8): out = logsoftmax(dinv[n]*sum srow2[s]*h2q[s]+b2)
// 16 lanes/node (4 ch each, u32 = full 64 B row = 1 line), 8-edge unroll.
__global__ __launch_bounds__(256) void gather2_fused(const int* __restrict__ cnt,
                                                     const int* __restrict__ ell,
                                                     const float* __restrict__ dinv,
                                                     const float* __restrict__ srow2,
                                                     const s8* __restrict__ h2q,
                                                     const float* __restrict__ b2,
                                                     float* __restrict__ out) {
    int node = blockIdx.x * 16 + (threadIdx.x >> 4);     // grid exact: N%16==0
    int q = threadIdx.x & 15;
    int len = cnt[node];
    const int* rowp = ell + (size_t)node * ELL_W;
    float acc[4] = {};
    int e = 0;
    for (; e + 3 < len; e += 4) {
        int s0 = rowp[e], s1 = rowp[e + 1], s2 = rowp[e + 2], s3 = rowp[e + 3];
        float w0 = srow2[s0], w1 = srow2[s1], w2 = srow2[s2], w3 = srow2[s3];
        u32 d0 = *(const u32*)(h2q + (size_t)s0 * H2_B + q * 4);
        u32 d1 = *(const u32*)(h2q + (size_t)s1 * H2_B + q * 4);
        u32 d2 = *(const u32*)(h2q + (size_t)s2 * H2_B + q * 4);
        u32 d3 = *(const u32*)(h2q + (size_t)s3 * H2_B + q * 4);
        qfma4(acc, d0, w0); qfma4(acc, d1, w1);
        qfma4(acc, d2, w2); qfma4(acc, d3, w3);
    }
    for (; e < len; ++e) {
        int s = rowp[e];
        float wv = srow2[s];
        u32 d = *(const u32*)(h2q + (size_t)s * H2_B + q * 4);
        qfma4(acc, d, wv);
    }
    float dd = dinv[node];
    float4 r;
    float m = -INFINITY;
    if (q < 10) {
        float4 bv = *(const float4*)(b2 + q * 4);
        r.x = fmaf(acc[0], dd, bv.x); r.y = fmaf(acc[1], dd, bv.y);
        r.z = fmaf(acc[2], dd, bv.z); r.w = fmaf(acc[3], dd, bv.w);
        m = fmaxf(fmaxf(r.x, r.y), fmaxf(r.z, r.w));
    }
    #pragma unroll
    for (int off = 1; off < 16; off <<= 1) m = fmaxf(m, __shfl_xor(m, off, 16));
    float ex = 0.f;
    if (q < 10)
        ex = expf(r.x - m) + expf(r.y - m) + expf(r.z - m) + expf(r.w - m);
    #pragma unroll
    for (int off = 1; off < 16; off <<= 1) ex += __shfl_xor(ex, off, 16);
    float lse = logf(ex) + m;
    if (q < 10) {
        float4 o = {r.x - lse, r.y - lse, r.z - lse, r.w - lse};
        *(float4*)(out + (size_t)node * C_OUT + q * 4) = o;
    }
}

// ---------------- launch ----------------
extern "C" void kernel_launch(void* const* d_in, const int* in_sizes, int n_in,
                              void* d_out, int out_size, void* d_ws, size_t ws_size,
                              hipStream_t stream) {
    const float* x     = (const float*)d_in[0];
    const int*   eidx  = (const int*)d_in[1];
    const float* W1    = (const float*)d_in[2];
    const float* b1    = (const float*)d_in[3];
    const float* gamma = (const float*)d_in[4];
    const float* beta  = (const float*)d_in[5];
    const float* W2    = (const float*)d_in[6];
    const float* b2    = (const float*)d_in[7];
    float* out = (float*)d_out;

    const int* src = eidx;
    const int* dst = eidx + N_EDGES;

    // workspace layout (dword units)
    float* ws = (float*)d_ws;
    float* dinv    = ws;                        // N
    int*   cnt     = (int*)(ws + 100000);       // N
    int*   bcur    = (int*)(ws + 200000);       // NBKT*16 (+pad)
    int*   ell     = (int*)(ws + 203200);       // N*64 = 6.4M
    s8*    xq      = (s8*)(ws + 6603200);       // N*128 int8 = 3.2M dwords
    float* qs1     = ws + 9803200;              // N   (s_row -> qscale1 in place)
    float* srow2   = ws + 9903200;              // N
    u16*   aggb    = (u16*)(ws + 10003200);     // N*128 bf16 = 6.4M dwords
    int2*  region  = (int2*)(ws + 10003200);    // aliases aggb (dead before gather_x)
    u16*   hb      = (u16*)(ws + 16403200);     // N*128 bf16 = 6.4M dwords
    u16*   W1t     = (u16*)(ws + 22803200);     // 8192 dwords
    s8*    h2q     = (s8*)(ws + 22811392);      // N*64 int8 = 1.6M dwords
    float* pstats  = ws + 24411392;             // 256*800
    float* scale   = ws + 24616192;             // 128
    float* shift   = ws + 24616320;             // 128
    float* K       = ws + 24616448;             // 64
    u16*   W2t     = (u16*)(ws + 24616512);     // 3072 dwords

    size_t needed = (size_t)(24616512 + 3072 + 256) * 4;   // ~98.5 MB (<= 99.2 proven)
    if (ws_size < needed) return;

    // prep: x-quant + wconvert overlap the bucket scatter in one kernel
    hipMemsetAsync(bcur, 0, NBKT * CNT_STRIDE * 4, stream);
    fused_prep<<<P_NB + FP_WCV_NB + FP_XQ_NB, 256, 0, stream>>>(
        x, W1, src, dst, bcur, region, xq, qs1, W1t);
    ell_build<<<NBKT, 256, 0, stream>>>(bcur, region, ell, cnt, dinv, qs1);

    // layer 1
    gather_x<<<N_NODES / 16, 256, 0, stream>>>(cnt, ell, dinv, qs1, xq, aggb);
    gemm1_mfma<<<G1_NB, 256, 0, stream>>>(aggb, W1t, b1, hb, pstats);
    stats_final<<<128, 256, 0, stream>>>(pstats, gamma, beta, scale, shift);
    w2fold<<<48, 128, 0, stream>>>(W2, scale, shift, W2t, K);

    // layer 2
    gemm2_mfma<<<G2_NB, 256, 0, stream>>>(hb, W2t, K, dinv, h2q, srow2);
    gather2_fused<<<N_NODES / 16, 256, 0, stream>>>(cnt, ell, dinv, srow2, h2q, b2, out);
}

// Round 14
// 169.569 us; speedup vs baseline: 1.2799x; 1.0295x over previous
//
#include <hip/hip_runtime.h>
#include <math.h>

#define N_NODES 100000
#define N_EDGES 1600000
#define F_IN 128
#define H_DIM 128
#define C_OUT 40
#define BN_EPS 1e-5f

#define ELL_W 64           // slots per node; Poisson(16) => P(deg>63) ~ 1e-17
#define CNT_STRIDE 16      // bcur padding: one cursor per 64B line

#define BKT_W 512          // nodes per coarse bucket
#define NBKT ((N_NODES + BKT_W - 1) / BKT_W)            // 196
#define BKT_CAP 12288      // edges capacity per bucket (mean 8163, +45 sigma)
#define P_EDGES 4096       // edges per scatter block (16/thread)
#define P_NB ((N_EDGES + P_EDGES - 1) / P_EDGES)        // 391
#define FP_WCV_NB 64       // wconvert blocks
#define FP_XQ_NB 6250      // x-quantize blocks (16 rows/block)

#define G1_ROWS 128
#define G1_LD 136          // shorts: 272 B row
#define G1_NB ((N_NODES + G1_ROWS - 1) / G1_ROWS)       // 782
#define PS_LD 800          // pstats stride (>= G1_NB)
#define G2_ROWS 128
#define G2_NB ((N_NODES + G2_ROWS - 1) / G2_ROWS)       // 782
#define H2_B 64            // h2q row bytes (40 int8 + 24 zero pad = 1 line)

typedef unsigned short u16;
typedef unsigned int u32;
typedef signed char s8;
typedef __attribute__((ext_vector_type(8))) __bf16 bf16x8;
typedef __attribute__((ext_vector_type(4))) float f32x4;

__device__ __forceinline__ u16 f2bf(float f) {              // RNE
    u32 u = __float_as_uint(f);
    u += 0x7FFFu + ((u >> 16) & 1u);
    return (u16)(u >> 16);
}
// 4 packed int8 -> 4 f32 fma (bfe + cvt + fma each)
__device__ __forceinline__ void qfma4(float* a, u32 d, float w) {
    a[0] = fmaf((float)((int)(d << 24) >> 24), w, a[0]);
    a[1] = fmaf((float)((int)(d << 16) >> 24), w, a[1]);
    a[2] = fmaf((float)((int)(d <<  8) >> 24), w, a[2]);
    a[3] = fmaf((float)((int)d >> 24),         w, a[3]);
}
__device__ __forceinline__ u32 pack4(int q0, int q1, int q2, int q3) {
    return (u32)(q0 & 255) | ((u32)(q1 & 255) << 8) |
           ((u32)(q2 & 255) << 16) | ((u32)(q3 & 255) << 24);
}

// ---- fused prep: [0,P_NB) sorted bucket_scatter | [+64) wconvert | rest x-quant
// Scatter blocks LDS-sort their 4096 edges by bucket so region writes are
// coalesced runs; edge record packed to u32 (local_dst 9b << 17 | src 17b).
__global__ __launch_bounds__(256) void fused_prep(const float* __restrict__ x,
                                                  const float* __restrict__ W1,
                                                  const int* __restrict__ src,
                                                  const int* __restrict__ dst,
                                                  int* __restrict__ bcur,
                                                  u32* __restrict__ region,
                                                  s8* __restrict__ xq,
                                                  float* __restrict__ qs1,
                                                  u16* __restrict__ W1t) {
    __shared__ u32 stage[P_EDGES];        // 16 KB
    __shared__ u16 bkarr[P_EDGES];        // 8 KB
    __shared__ int lcnt[NBKT];            // counts -> rank cursors
    __shared__ int loffs[NBKT];
    __shared__ int baseaddr[NBKT];
    __shared__ int tmp[256];
    __shared__ int tot_sh;
    int b = blockIdx.x, t = threadIdx.x;
    if (b < P_NB) {
        // ---- phase A: histogram ----
        for (int i = t; i < NBKT; i += 256) lcnt[i] = 0;
        __syncthreads();
        int base = b * P_EDGES;
        #pragma unroll
        for (int i = 0; i < 16; ++i) {
            int idx = base + i * 256 + t;
            if (idx < N_EDGES) atomicAdd(&lcnt[dst[idx] >> 9], 1);
        }
        __syncthreads();
        // ---- phase B: scan + global reserve + zero ranks ----
        int v = (t < NBKT) ? lcnt[t] : 0;
        tmp[t] = v;
        __syncthreads();
        for (int off = 1; off < 256; off <<= 1) {
            int u = (t >= off) ? tmp[t - off] : 0;
            __syncthreads();
            tmp[t] += u;
            __syncthreads();
        }
        if (t < NBKT) {
            int lo = tmp[t] - v;
            loffs[t] = lo;
            int g = v ? atomicAdd(&bcur[t * CNT_STRIDE], v) : 0;
            baseaddr[t] = t * BKT_CAP + g - lo;
            lcnt[t] = 0;                  // becomes rank cursor
        }
        if (t == 255) tot_sh = tmp[255];
        __syncthreads();
        // ---- phase C: stage sorted by bucket ----
        #pragma unroll
        for (int i = 0; i < 16; ++i) {
            int idx = base + i * 256 + t;
            if (idx < N_EDGES) {
                int d = dst[idx];
                int bk = d >> 9;
                int rank = atomicAdd(&lcnt[bk], 1);
                int slot = loffs[bk] + rank;
                stage[slot] = ((u32)(d & 511) << 17) | (u32)src[idx];
                bkarr[slot] = (u16)bk;
            }
        }
        __syncthreads();
        // ---- phase D: coalesced write-out ----
        int tot = tot_sh;
        for (int j = t; j < tot; j += 256) {
            int bk = bkarr[j];
            int destp = baseaddr[bk] + j;
            if (destp - bk * BKT_CAP < BKT_CAP)   // statistically impossible; OOB guard
                region[destp] = stage[j];
        }
    } else if (b < P_NB + FP_WCV_NB) {
        // ---- wconvert: W1 [k][n] f32 -> W1t [n][k] bf16 ----
        int i = (b - P_NB) * 256 + t;     // < 16384
        int k = i >> 7, n = i & 127;
        W1t[n * H_DIM + k] = f2bf(W1[k * H_DIM + n]);
    } else {
        // ---- x int8 quantize, per-row scale: 16 lanes/row, 16 rows/block ----
        int row = (b - P_NB - FP_WCV_NB) * 16 + (t >> 4);   // < 100000 exactly
        int lane = t & 15;
        const float4* xr = (const float4*)(x + (size_t)row * F_IN + lane * 8);
        float4 a = xr[0], c = xr[1];
        float m = fmaxf(fmaxf(fmaxf(fabsf(a.x), fabsf(a.y)), fmaxf(fabsf(a.z), fabsf(a.w))),
                        fmaxf(fmaxf(fabsf(c.x), fabsf(c.y)), fmaxf(fabsf(c.z), fabsf(c.w))));
        #pragma unroll
        for (int off = 1; off < 16; off <<= 1) m = fmaxf(m, __shfl_xor(m, off, 16));
        m = fmaxf(m, 1e-20f);
        float inv = 127.f / m;
        u32 p0 = pack4((int)rintf(a.x * inv), (int)rintf(a.y * inv),
                       (int)rintf(a.z * inv), (int)rintf(a.w * inv));
        u32 p1 = pack4((int)rintf(c.x * inv), (int)rintf(c.y * inv),
                       (int)rintf(c.z * inv), (int)rintf(c.w * inv));
        uint2 p; p.x = p0; p.y = p1;
        *(uint2*)(xq + (size_t)row * F_IN + lane * 8) = p;
        if (lane == 0) qs1[row] = m / 127.f;     // s_row; dinv folded in ell_build
    }
}

// ---- per-bucket ELL build from packed u32 records ----
// Also finalizes dinv and qscale1 (= s_row * dinv) in place.
__global__ __launch_bounds__(256) void ell_build(const int* __restrict__ bcur,
                                                 const u32* __restrict__ region,
                                                 int* __restrict__ ell,
                                                 int* __restrict__ cnt,
                                                 float* __restrict__ dinv,
                                                 float* __restrict__ qs1) {
    __shared__ int lcnt[BKT_W];
    int b = blockIdx.x, t = threadIdx.x;
    int nbase = b * BKT_W;
    for (int i = t; i < BKT_W; i += 256) {
        lcnt[i] = 1;                      // self-loop occupies slot 0
        int node = nbase + i;
        if (node < N_NODES) ell[(size_t)node * ELL_W] = node;
    }
    __syncthreads();
    int ne = bcur[b * CNT_STRIDE];
    if (ne > BKT_CAP) ne = BKT_CAP;
    const u32* reg = region + (size_t)b * BKT_CAP;
    for (int i = t; i < ne; i += 256) {
        u32 p = reg[i];
        int ldst = (int)(p >> 17);
        int srcv = (int)(p & 0x1FFFFu);
        int rank = atomicAdd(&lcnt[ldst], 1);
        if (rank < ELL_W) ell[(size_t)(nbase + ldst) * ELL_W + rank] = srcv;
    }
    __syncthreads();
    for (int i = t; i < BKT_W; i += 256) {
        int node = nbase + i;
        if (node < N_NODES) {
            int c = lcnt[i];
            cnt[node] = (c > ELL_W) ? ELL_W : c;
            float dv = rsqrtf((float)c);   // true degree
            dinv[node] = dv;
            qs1[node] *= dv;               // qscale1 = s_row * dinv  (in place)
        }
    }
}

// ------- gather layer 1 (int8): aggb[n] = bf16( dinv[n]*sum qs1[s]*xq[s] ) --
// 16 lanes/node (8 ch each, uint2 = 8 B), 16 nodes/block, 4-edge unroll.
__global__ __launch_bounds__(256) void gather_x(const int* __restrict__ cnt,
                                                const int* __restrict__ ell,
                                                const float* __restrict__ dinv,
                                                const float* __restrict__ qs1,
                                                const s8* __restrict__ xq,
                                                u16* __restrict__ aggb) {
    int node = blockIdx.x * 16 + (threadIdx.x >> 4);     // grid exact: N%16==0
    int q = threadIdx.x & 15;
    int len = cnt[node];
    const int* rowp = ell + (size_t)node * ELL_W;
    float acc[8] = {};
    int e = 0;
    for (; e + 3 < len; e += 4) {
        int s0 = rowp[e], s1 = rowp[e + 1], s2 = rowp[e + 2], s3 = rowp[e + 3];
        float w0 = qs1[s0], w1 = qs1[s1], w2 = qs1[s2], w3 = qs1[s3];
        uint2 v0 = *(const uint2*)(xq + (size_t)s0 * F_IN + q * 8);
        uint2 v1 = *(const uint2*)(xq + (size_t)s1 * F_IN + q * 8);
        uint2 v2 = *(const uint2*)(xq + (size_t)s2 * F_IN + q * 8);
        uint2 v3 = *(const uint2*)(xq + (size_t)s3 * F_IN + q * 8);
        qfma4(acc, v0.x, w0); qfma4(acc + 4, v0.y, w0);
        qfma4(acc, v1.x, w1); qfma4(acc + 4, v1.y, w1);
        qfma4(acc, v2.x, w2); qfma4(acc + 4, v2.y, w2);
        qfma4(acc, v3.x, w3); qfma4(acc + 4, v3.y, w3);
    }
    for (; e < len; ++e) {
        int s = rowp[e];
        float wv = qs1[s];
        uint2 v = *(const uint2*)(xq + (size_t)s * F_IN + q * 8);
        qfma4(acc, v.x, wv); qfma4(acc + 4, v.y, wv);
    }
    float dd = dinv[node];
    int4 o;
    o.x = (int)((u32)f2bf(acc[0] * dd) | ((u32)f2bf(acc[1] * dd) << 16));
    o.y = (int)((u32)f2bf(acc[2] * dd) | ((u32)f2bf(acc[3] * dd) << 16));
    o.z = (int)((u32)f2bf(acc[4] * dd) | ((u32)f2bf(acc[5] * dd) << 16));
    o.w = (int)((u32)f2bf(acc[6] * dd) | ((u32)f2bf(acc[7] * dd) << 16));
    *(int4*)(aggb + (size_t)node * H_DIM + q * 8) = o;
}

// ------------- GEMM1 via MFMA: hb = relu(aggb@W1 + b1) (bf16) --------------
__global__ __launch_bounds__(256) void gemm1_mfma(const u16* __restrict__ aggb,
                                                  const u16* __restrict__ W1t,
                                                  const float* __restrict__ b1,
                                                  u16* __restrict__ hb,
                                                  float* __restrict__ pstats) {
    __shared__ u16 As[G1_ROWS * G1_LD];   // 34.8 KB
    int tid = threadIdx.x;
    int base = blockIdx.x * G1_ROWS;

    {   // stage 128 node rows (256 B each), clamped at tail
        int row = tid >> 1, half = tid & 1;
        int gr = base + row; if (gr >= N_NODES) gr = N_NODES - 1;
        const int4* gsrc = (const int4*)(aggb + (size_t)gr * H_DIM + half * 64);
        int4* ldst = (int4*)(As + row * G1_LD + half * 64);
        #pragma unroll
        for (int i = 0; i < 8; ++i) ldst[i] = gsrc[i];
    }
    __syncthreads();

    int lane = tid & 63, w = tid >> 6;
    int r = lane & 15, g = lane >> 4;

    bf16x8 wf[2][4];   // [ch-tile][kstep], resident
    #pragma unroll
    for (int t = 0; t < 2; ++t)
        #pragma unroll
        for (int ks = 0; ks < 4; ++ks)
            wf[t][ks] = *(const bf16x8*)(W1t + (w * 32 + t * 16 + r) * H_DIM + ks * 32 + g * 8);

    float bch[2][4];
    #pragma unroll
    for (int t = 0; t < 2; ++t)
        #pragma unroll
        for (int i = 0; i < 4; ++i)
            bch[t][i] = b1[w * 32 + t * 16 + 4 * g + i];

    float cs[8] = {}, cq[8] = {};

    for (int rt = 0; rt < 8; ++rt) {
        f32x4 acc0 = {0.f, 0.f, 0.f, 0.f}, acc1 = {0.f, 0.f, 0.f, 0.f};
        #pragma unroll
        for (int ks = 0; ks < 4; ++ks) {
            bf16x8 nf = *(const bf16x8*)(As + (rt * 16 + r) * G1_LD + ks * 32 + g * 8);
            acc0 = __builtin_amdgcn_mfma_f32_16x16x32_bf16(wf[0][ks], nf, acc0, 0, 0, 0);
            acc1 = __builtin_amdgcn_mfma_f32_16x16x32_bf16(wf[1][ks], nf, acc1, 0, 0, 0);
        }
        int node = base + rt * 16 + r;
        if (node < N_NODES) {
            float o0[4], o1[4];
            #pragma unroll
            for (int i = 0; i < 4; ++i) {
                o0[i] = fmaxf(acc0[i] + bch[0][i], 0.f);
                o1[i] = fmaxf(acc1[i] + bch[1][i], 0.f);
                cs[i]     += o0[i]; cq[i]     += o0[i] * o0[i];
                cs[4 + i] += o1[i]; cq[4 + i] += o1[i] * o1[i];
            }
            uint2 p0, p1;
            p0.x = (u32)f2bf(o0[0]) | ((u32)f2bf(o0[1]) << 16);
            p0.y = (u32)f2bf(o0[2]) | ((u32)f2bf(o0[3]) << 16);
            p1.x = (u32)f2bf(o1[0]) | ((u32)f2bf(o1[1]) << 16);
            p1.y = (u32)f2bf(o1[2]) | ((u32)f2bf(o1[3]) << 16);
            u16* hp = hb + (size_t)node * H_DIM + w * 32 + 4 * g;
            *(uint2*)hp = p0;
            *(uint2*)(hp + 16) = p1;
        }
    }

    #pragma unroll
    for (int j = 0; j < 8; ++j) {
        #pragma unroll
        for (int m = 1; m < 16; m <<= 1) {
            cs[j] += __shfl_xor(cs[j], m, 16);
            cq[j] += __shfl_xor(cq[j], m, 16);
        }
    }
    if (r == 0) {
        #pragma unroll
        for (int j = 0; j < 8; ++j) {
            int c = w * 32 + (j >> 2) * 16 + 4 * g + (j & 3);
            pstats[c * PS_LD + blockIdx.x] = cs[j];
            pstats[(128 + c) * PS_LD + blockIdx.x] = cq[j];
        }
    }
}

// ---- reduce per-block partials -> scale/shift (one block per channel) ----
__global__ __launch_bounds__(256) void stats_final(const float* __restrict__ pstats,
                                                   const float* __restrict__ gamma,
                                                   const float* __restrict__ beta,
                                                   float* __restrict__ scale,
                                                   float* __restrict__ shift) {
    __shared__ float ls[256], lq[256];
    int c = blockIdx.x, t = threadIdx.x;
    float s = 0.f, q = 0.f;
    for (int b = t; b < G1_NB; b += 256) {
        s += pstats[c * PS_LD + b];
        q += pstats[(128 + c) * PS_LD + b];
    }
    ls[t] = s; lq[t] = q;
    __syncthreads();
    for (int off = 128; off; off >>= 1) {
        if (t < off) { ls[t] += ls[t + off]; lq[t] += lq[t + off]; }
        __syncthreads();
    }
    if (t == 0) {
        const float invn = 1.0f / (float)N_NODES;
        float mean = ls[0] * invn;
        float var = lq[0] * invn - mean * mean;
        float sc = gamma[c] * rsqrtf(var + BN_EPS);
        scale[c] = sc;
        shift[c] = beta[c] - mean * sc;
    }
}

// ---- fold BN into layer-2 weights; one block per padded channel c<48 ----
__global__ __launch_bounds__(128) void w2fold(const float* __restrict__ W2,
                                              const float* __restrict__ scale,
                                              const float* __restrict__ shift,
                                              u16* __restrict__ W2t,
                                              float* __restrict__ K) {
    __shared__ float red[128];
    int c = blockIdx.x, k = threadIdx.x;
    float wv = (c < C_OUT) ? W2[k * C_OUT + c] : 0.f;
    W2t[c * H_DIM + k] = (c < C_OUT) ? f2bf(scale[k] * wv) : (u16)0;
    red[k] = shift[k] * wv;
    __syncthreads();
    for (int off = 64; off; off >>= 1) {
        if (k < off) red[k] += red[k + off];
        __syncthreads();
    }
    if (k == 0) K[c] = red[0];
}

// ---- GEMM2 via MFMA -> int8 row-quantized h2q (64 B rows incl. zero pad) ---
__global__ __launch_bounds__(256) void gemm2_mfma(const u16* __restrict__ hb,
                                                  const u16* __restrict__ W2t,
                                                  const float* __restrict__ K,
                                                  const float* __restrict__ dinv,
                                                  s8* __restrict__ h2q,
                                                  float* __restrict__ srow2) {
    __shared__ u16 As[G2_ROWS * G1_LD];
    int tid = threadIdx.x;
    int base = blockIdx.x * G2_ROWS;

    {
        int row = tid >> 1, half = tid & 1;
        int gr = base + row; if (gr >= N_NODES) gr = N_NODES - 1;
        const int4* gsrc = (const int4*)(hb + (size_t)gr * H_DIM + half * 64);
        int4* ldst = (int4*)(As + row * G1_LD + half * 64);
        #pragma unroll
        for (int i = 0; i < 8; ++i) ldst[i] = gsrc[i];
    }
    __syncthreads();

    int lane = tid & 63, w = tid >> 6;
    int r = lane & 15, g = lane >> 4;

    bf16x8 wf[3][4];
    #pragma unroll
    for (int t = 0; t < 3; ++t)
        #pragma unroll
        for (int ks = 0; ks < 4; ++ks)
            wf[t][ks] = *(const bf16x8*)(W2t + (t * 16 + r) * H_DIM + ks * 32 + g * 8);

    float kv[3][4];
    #pragma unroll
    for (int t = 0; t < 3; ++t)
        #pragma unroll
        for (int i = 0; i < 4; ++i)
            kv[t][i] = K[t * 16 + 4 * g + i];

    f32x4 acc[2][3];
    #pragma unroll
    for (int i2 = 0; i2 < 2; ++i2)
        #pragma unroll
        for (int t = 0; t < 3; ++t)
            acc[i2][t] = (f32x4){0.f, 0.f, 0.f, 0.f};

    #pragma unroll
    for (int i2 = 0; i2 < 2; ++i2) {
        int rt = 2 * w + i2;
        #pragma unroll
        for (int ks = 0; ks < 4; ++ks) {
            bf16x8 nf = *(const bf16x8*)(As + (rt * 16 + r) * G1_LD + ks * 32 + g * 8);
            acc[i2][0] = __builtin_amdgcn_mfma_f32_16x16x32_bf16(wf[0][ks], nf, acc[i2][0], 0, 0, 0);
            acc[i2][1] = __builtin_amdgcn_mfma_f32_16x16x32_bf16(wf[1][ks], nf, acc[i2][1], 0, 0, 0);
            acc[i2][2] = __builtin_amdgcn_mfma_f32_16x16x32_bf16(wf[2][ks], nf, acc[i2][2], 0, 0, 0);
        }
    }

    #pragma unroll
    for (int i2 = 0; i2 < 2; ++i2) {
        int node = base + (2 * w + i2) * 16 + r;
        float dd = (node < N_NODES) ? dinv[node] : 0.f;
        float v[3][4];
        float m = 0.f;
        #pragma unroll
        for (int t = 0; t < 3; ++t)
            #pragma unroll
            for (int i = 0; i < 4; ++i) {
                v[t][i] = (acc[i2][t][i] + kv[t][i]) * dd;
                if (t < 2 || g < 2) m = fmaxf(m, fabsf(v[t][i]));
            }
        m = fmaxf(m, __shfl_xor(m, 16));     // across g pairs
        m = fmaxf(m, __shfl_xor(m, 32));
        m = fmaxf(m, 1e-20f);
        float inv = 127.f / m;
        if (node < N_NODES) {
            s8* hp = h2q + (size_t)node * H2_B;
            #pragma unroll
            for (int t = 0; t < 2; ++t) {
                u32 p = pack4((int)rintf(v[t][0] * inv), (int)rintf(v[t][1] * inv),
                              (int)rintf(v[t][2] * inv), (int)rintf(v[t][3] * inv));
                *(u32*)(hp + t * 16 + 4 * g) = p;
            }
            u32 p2 = (g < 2) ? pack4((int)rintf(v[2][0] * inv), (int)rintf(v[2][1] * inv),
                                     (int)rintf(v[2][2] * inv), (int)rintf(v[2][3] * inv))
                             : 0u;
            *(u32*)(hp + 32 + 4 * g) = p2;       // g>=2 zeroes ch 40-47
            *(u32*)(hp + 48 + 4 * g) = 0u;       // ch 48-63 zero
            if (g == 0) srow2[node] = m / 127.f;
        }
    }
}

// --- gather layer 2 (int8): out = logsoftmax(dinv[n]*sum srow2[s]*h2q[s]+b2)
// 16 lanes/node (4 ch each, u32 = full 64 B row = 1 line), 4-edge unroll.
__global__ __launch_bounds__(256) void gather2_fused(const int* __restrict__ cnt,
                                                     const int* __restrict__ ell,
                                                     const float* __restrict__ dinv,
                                                     const float* __restrict__ srow2,
                                                     const s8* __restrict__ h2q,
                                                     const float* __restrict__ b2,
                                                     float* __restrict__ out) {
    int node = blockIdx.x * 16 + (threadIdx.x >> 4);     // grid exact: N%16==0
    int q = threadIdx.x & 15;
    int len = cnt[node];
    const int* rowp = ell + (size_t)node * ELL_W;
    float acc[4] = {};
    int e = 0;
    for (; e + 3 < len; e += 4) {
        int s0 = rowp[e], s1 = rowp[e + 1], s2 = rowp[e + 2], s3 = rowp[e + 3];
        float w0 = srow2[s0], w1 = srow2[s1], w2 = srow2[s2], w3 = srow2[s3];
        u32 d0 = *(const u32*)(h2q + (size_t)s0 * H2_B + q * 4);
        u32 d1 = *(const u32*)(h2q + (size_t)s1 * H2_B + q * 4);
        u32 d2 = *(const u32*)(h2q + (size_t)s2 * H2_B + q * 4);
        u32 d3 = *(const u32*)(h2q + (size_t)s3 * H2_B + q * 4);
        qfma4(acc, d0, w0); qfma4(acc, d1, w1);
        qfma4(acc, d2, w2); qfma4(acc, d3, w3);
    }
    for (; e < len; ++e) {
        int s = rowp[e];
        float wv = srow2[s];
        u32 d = *(const u32*)(h2q + (size_t)s * H2_B + q * 4);
        qfma4(acc, d, wv);
    }
    float dd = dinv[node];
    float4 r;
    float m = -INFINITY;
    if (q < 10) {
        float4 bv = *(const float4*)(b2 + q * 4);
        r.x = fmaf(acc[0], dd, bv.x); r.y = fmaf(acc[1], dd, bv.y);
        r.z = fmaf(acc[2], dd, bv.z); r.w = fmaf(acc[3], dd, bv.w);
        m = fmaxf(fmaxf(r.x, r.y), fmaxf(r.z, r.w));
    }
    #pragma unroll
    for (int off = 1; off < 16; off <<= 1) m = fmaxf(m, __shfl_xor(m, off, 16));
    float ex = 0.f;
    if (q < 10)
        ex = expf(r.x - m) + expf(r.y - m) + expf(r.z - m) + expf(r.w - m);
    #pragma unroll
    for (int off = 1; off < 16; off <<= 1) ex += __shfl_xor(ex, off, 16);
    float lse = logf(ex) + m;
    if (q < 10) {
        float4 o = {r.x - lse, r.y - lse, r.z - lse, r.w - lse};
        *(float4*)(out + (size_t)node * C_OUT + q * 4) = o;
    }
}

// ---------------- launch ----------------
extern "C" void kernel_launch(void* const* d_in, const int* in_sizes, int n_in,
                              void* d_out, int out_size, void* d_ws, size_t ws_size,
                              hipStream_t stream) {
    const float* x     = (const float*)d_in[0];
    const int*   eidx  = (const int*)d_in[1];
    const float* W1    = (const float*)d_in[2];
    const float* b1    = (const float*)d_in[3];
    const float* gamma = (const float*)d_in[4];
    const float* beta  = (const float*)d_in[5];
    const float* W2    = (const float*)d_in[6];
    const float* b2    = (const float*)d_in[7];
    float* out = (float*)d_out;

    const int* src = eidx;
    const int* dst = eidx + N_EDGES;

    // workspace layout (dword units)
    float* ws = (float*)d_ws;
    float* dinv    = ws;                        // N
    int*   cnt     = (int*)(ws + 100000);       // N
    int*   bcur    = (int*)(ws + 200000);       // NBKT*16 (+pad)
    int*   ell     = (int*)(ws + 203200);       // N*64 = 6.4M
    s8*    xq      = (s8*)(ws + 6603200);       // N*128 int8 = 3.2M dwords
    float* qs1     = ws + 9803200;              // N   (s_row -> qscale1 in place)
    float* srow2   = ws + 9903200;              // N
    u16*   aggb    = (u16*)(ws + 10003200);     // N*128 bf16 = 6.4M dwords
    u32*   region  = (u32*)(ws + 10003200);     // aliases aggb: NBKT*BKT_CAP u32 = 2.41M dwords
    u16*   hb      = (u16*)(ws + 16403200);     // N*128 bf16 = 6.4M dwords
    u16*   W1t     = (u16*)(ws + 22803200);     // 8192 dwords
    s8*    h2q     = (s8*)(ws + 22811392);      // N*64 int8 = 1.6M dwords
    float* pstats  = ws + 24411392;             // 256*800
    float* scale   = ws + 24616192;             // 128
    float* shift   = ws + 24616320;             // 128
    float* K       = ws + 24616448;             // 64
    u16*   W2t     = (u16*)(ws + 24616512);     // 3072 dwords

    size_t needed = (size_t)(24616512 + 3072 + 256) * 4;   // ~98.5 MB (<= 99.2 proven)
    if (ws_size < needed) return;

    // prep: x-quant + wconvert overlap the sorted bucket scatter in one kernel
    hipMemsetAsync(bcur, 0, NBKT * CNT_STRIDE * 4, stream);
    fused_prep<<<P_NB + FP_WCV_NB + FP_XQ_NB, 256, 0, stream>>>(
        x, W1, src, dst, bcur, region, xq, qs1, W1t);
    ell_build<<<NBKT, 256, 0, stream>>>(bcur, region, ell, cnt, dinv, qs1);

    // layer 1
    gather_x<<<N_NODES / 16, 256, 0, stream>>>(cnt, ell, dinv, qs1, xq, aggb);
    gemm1_mfma<<<G1_NB, 256, 0, stream>>>(aggb, W1t, b1, hb, pstats);
    stats_final<<<128, 256, 0, stream>>>(pstats, gamma, beta, scale, shift);
    w2fold<<<48, 128, 0, stream>>>(W2, scale, shift, W2t, K);

    // layer 2
    gemm2_mfma<<<G2_NB, 256, 0, stream>>>(hb, W2t, K, dinv, h2q, srow2);
    gather2_fused<<<N_NODES / 16, 256, 0, stream>>>(cnt, ell, dinv, srow2, h2q, b2, out);
}

// Round 15
// 168.528 us; speedup vs baseline: 1.2878x; 1.0062x over previous
//
#include <hip/hip_runtime.h>
#include <math.h>

#define N_NODES 100000
#define N_EDGES 1600000
#define F_IN 128
#define H_DIM 128
#define C_OUT 40
#define BN_EPS 1e-5f

#define ELL_W 64           // slots per node; Poisson(16) => P(deg>63) ~ 1e-17
#define CNT_STRIDE 16      // bcur padding: one cursor per 64B line

#define BKT_W 512          // nodes per coarse bucket
#define NBKT ((N_NODES + BKT_W - 1) / BKT_W)            // 196
#define BKT_CAP 12288      // edges capacity per bucket (mean 8163, +45 sigma)
#define P_EDGES 2048       // edges per scatter block (8/thread, held in regs)
#define P_NB ((N_EDGES + P_EDGES - 1) / P_EDGES)        // 782
#define FP_WCV_NB 64       // wconvert blocks
#define FP_XQ_NB 6250      // x-quantize blocks (16 rows/block)

#define G1_ROWS 128
#define G1_LD 136          // shorts: 272 B row
#define G1_NB ((N_NODES + G1_ROWS - 1) / G1_ROWS)       // 782
#define PS_LD 800          // pstats stride (>= G1_NB)
#define G2_ROWS 128
#define G2_NB ((N_NODES + G2_ROWS - 1) / G2_ROWS)       // 782
#define H2_B 64            // h2q row bytes (40 int8 + 24 zero pad = 1 line)

typedef unsigned short u16;
typedef unsigned int u32;
typedef signed char s8;
typedef __attribute__((ext_vector_type(8))) __bf16 bf16x8;
typedef __attribute__((ext_vector_type(4))) float f32x4;

__device__ __forceinline__ u16 f2bf(float f) {              // RNE
    u32 u = __float_as_uint(f);
    u += 0x7FFFu + ((u >> 16) & 1u);
    return (u16)(u >> 16);
}
// 4 packed int8 -> 4 f32 fma (bfe + cvt + fma each)
__device__ __forceinline__ void qfma4(float* a, u32 d, float w) {
    a[0] = fmaf((float)((int)(d << 24) >> 24), w, a[0]);
    a[1] = fmaf((float)((int)(d << 16) >> 24), w, a[1]);
    a[2] = fmaf((float)((int)(d <<  8) >> 24), w, a[2]);
    a[3] = fmaf((float)((int)d >> 24),         w, a[3]);
}
__device__ __forceinline__ u32 pack4(int q0, int q1, int q2, int q3) {
    return (u32)(q0 & 255) | ((u32)(q1 & 255) << 8) |
           ((u32)(q2 & 255) << 16) | ((u32)(q3 & 255) << 24);
}

// ---- fused prep: [0,P_NB) sorted bucket_scatter | [+64) wconvert | rest x-quant
// Scatter blocks LDS-sort their 2048 edges by bucket (dst kept in registers;
// read once). Edge record packed to u32 (local_dst 9b << 17 | src 17b).
__global__ __launch_bounds__(256) void fused_prep(const float* __restrict__ x,
                                                  const float* __restrict__ W1,
                                                  const int* __restrict__ src,
                                                  const int* __restrict__ dst,
                                                  int* __restrict__ bcur,
                                                  u32* __restrict__ region,
                                                  s8* __restrict__ xq,
                                                  float* __restrict__ qs1,
                                                  u16* __restrict__ W1t) {
    __shared__ u32 stage[P_EDGES];        // 8 KB
    __shared__ u16 bkarr[P_EDGES];        // 4 KB
    __shared__ int lcnt[NBKT];            // counts -> rank cursors
    __shared__ int loffs[NBKT];
    __shared__ int baseaddr[NBKT];
    __shared__ int tmp[256];
    __shared__ int tot_sh;
    int b = blockIdx.x, t = threadIdx.x;
    if (b < P_NB) {
        // ---- phase A: histogram (dst kept in registers) ----
        for (int i = t; i < NBKT; i += 256) lcnt[i] = 0;
        __syncthreads();
        int base = b * P_EDGES;
        int d[8];
        #pragma unroll
        for (int i = 0; i < 8; ++i) {
            int idx = base + i * 256 + t;
            if (idx < N_EDGES) {
                d[i] = dst[idx];
                atomicAdd(&lcnt[d[i] >> 9], 1);
            } else d[i] = -1;
        }
        __syncthreads();
        // ---- phase B: scan + global reserve + zero ranks ----
        int v = (t < NBKT) ? lcnt[t] : 0;
        tmp[t] = v;
        __syncthreads();
        for (int off = 1; off < 256; off <<= 1) {
            int u = (t >= off) ? tmp[t - off] : 0;
            __syncthreads();
            tmp[t] += u;
            __syncthreads();
        }
        if (t < NBKT) {
            int lo = tmp[t] - v;
            loffs[t] = lo;
            int g = v ? atomicAdd(&bcur[t * CNT_STRIDE], v) : 0;
            baseaddr[t] = t * BKT_CAP + g - lo;
            lcnt[t] = 0;                  // becomes rank cursor
        }
        if (t == 255) tot_sh = tmp[255];
        __syncthreads();
        // ---- phase C: stage sorted by bucket (src read once) ----
        #pragma unroll
        for (int i = 0; i < 8; ++i) {
            int idx = base + i * 256 + t;
            if (d[i] >= 0) {
                int bk = d[i] >> 9;
                int rank = atomicAdd(&lcnt[bk], 1);
                int slot = loffs[bk] + rank;
                stage[slot] = ((u32)(d[i] & 511) << 17) | (u32)src[idx];
                bkarr[slot] = (u16)bk;
            }
        }
        __syncthreads();
        // ---- phase D: coalesced write-out ----
        int tot = tot_sh;
        for (int j = t; j < tot; j += 256) {
            int bk = bkarr[j];
            int destp = baseaddr[bk] + j;
            if (destp - bk * BKT_CAP < BKT_CAP)   // statistically impossible; OOB guard
                region[destp] = stage[j];
        }
    } else if (b < P_NB + FP_WCV_NB) {
        // ---- wconvert: W1 [k][n] f32 -> W1t [n][k] bf16 ----
        int i = (b - P_NB) * 256 + t;     // < 16384
        int k = i >> 7, n = i & 127;
        W1t[n * H_DIM + k] = f2bf(W1[k * H_DIM + n]);
    } else {
        // ---- x int8 quantize, per-row scale: 16 lanes/row, 16 rows/block ----
        int row = (b - P_NB - FP_WCV_NB) * 16 + (t >> 4);   // < 100000 exactly
        int lane = t & 15;
        const float4* xr = (const float4*)(x + (size_t)row * F_IN + lane * 8);
        float4 a = xr[0], c = xr[1];
        float m = fmaxf(fmaxf(fmaxf(fabsf(a.x), fabsf(a.y)), fmaxf(fabsf(a.z), fabsf(a.w))),
                        fmaxf(fmaxf(fabsf(c.x), fabsf(c.y)), fmaxf(fabsf(c.z), fabsf(c.w))));
        #pragma unroll
        for (int off = 1; off < 16; off <<= 1) m = fmaxf(m, __shfl_xor(m, off, 16));
        m = fmaxf(m, 1e-20f);
        float inv = 127.f / m;
        u32 p0 = pack4((int)rintf(a.x * inv), (int)rintf(a.y * inv),
                       (int)rintf(a.z * inv), (int)rintf(a.w * inv));
        u32 p1 = pack4((int)rintf(c.x * inv), (int)rintf(c.y * inv),
                       (int)rintf(c.z * inv), (int)rintf(c.w * inv));
        uint2 p; p.x = p0; p.y = p1;
        *(uint2*)(xq + (size_t)row * F_IN + lane * 8) = p;
        if (lane == 0) qs1[row] = m / 127.f;     // s_row; dinv folded in ell_build
    }
}

// ---- per-bucket ELL build from packed u32 records ----
// Also finalizes dinv and qscale1 (= s_row * dinv) in place.
__global__ __launch_bounds__(256) void ell_build(const int* __restrict__ bcur,
                                                 const u32* __restrict__ region,
                                                 int* __restrict__ ell,
                                                 int* __restrict__ cnt,
                                                 float* __restrict__ dinv,
                                                 float* __restrict__ qs1) {
    __shared__ int lcnt[BKT_W];
    int b = blockIdx.x, t = threadIdx.x;
    int nbase = b * BKT_W;
    for (int i = t; i < BKT_W; i += 256) {
        lcnt[i] = 1;                      // self-loop occupies slot 0
        int node = nbase + i;
        if (node < N_NODES) ell[(size_t)node * ELL_W] = node;
    }
    __syncthreads();
    int ne = bcur[b * CNT_STRIDE];
    if (ne > BKT_CAP) ne = BKT_CAP;
    const u32* reg = region + (size_t)b * BKT_CAP;
    for (int i = t; i < ne; i += 256) {
        u32 p = reg[i];
        int ldst = (int)(p >> 17);
        int srcv = (int)(p & 0x1FFFFu);
        int rank = atomicAdd(&lcnt[ldst], 1);
        if (rank < ELL_W) ell[(size_t)(nbase + ldst) * ELL_W + rank] = srcv;
    }
    __syncthreads();
    for (int i = t; i < BKT_W; i += 256) {
        int node = nbase + i;
        if (node < N_NODES) {
            int c = lcnt[i];
            cnt[node] = (c > ELL_W) ? ELL_W : c;
            float dv = rsqrtf((float)c);   // true degree
            dinv[node] = dv;
            qs1[node] *= dv;               // qscale1 = s_row * dinv  (in place)
        }
    }
}

// ------- gather layer 1 (int8): aggb[n] = bf16( dinv[n]*sum qs1[s]*xq[s] ) --
// 8 lanes/node (16 ch each, int4 = 16 B -> half the load count), 32 nodes/blk.
__global__ __launch_bounds__(256) void gather_x(const int* __restrict__ cnt,
                                                const int* __restrict__ ell,
                                                const float* __restrict__ dinv,
                                                const float* __restrict__ qs1,
                                                const s8* __restrict__ xq,
                                                u16* __restrict__ aggb) {
    int node = blockIdx.x * 32 + (threadIdx.x >> 3);     // grid exact: N%32==0
    int q = threadIdx.x & 7;
    int len = cnt[node];
    const int* rowp = ell + (size_t)node * ELL_W;
    float acc[16] = {};
    int e = 0;
    for (; e + 3 < len; e += 4) {
        int s0 = rowp[e], s1 = rowp[e + 1], s2 = rowp[e + 2], s3 = rowp[e + 3];
        float w0 = qs1[s0], w1 = qs1[s1], w2 = qs1[s2], w3 = qs1[s3];
        int4 v0 = *(const int4*)(xq + (size_t)s0 * F_IN + q * 16);
        int4 v1 = *(const int4*)(xq + (size_t)s1 * F_IN + q * 16);
        int4 v2 = *(const int4*)(xq + (size_t)s2 * F_IN + q * 16);
        int4 v3 = *(const int4*)(xq + (size_t)s3 * F_IN + q * 16);
        qfma4(acc, (u32)v0.x, w0); qfma4(acc + 4, (u32)v0.y, w0);
        qfma4(acc + 8, (u32)v0.z, w0); qfma4(acc + 12, (u32)v0.w, w0);
        qfma4(acc, (u32)v1.x, w1); qfma4(acc + 4, (u32)v1.y, w1);
        qfma4(acc + 8, (u32)v1.z, w1); qfma4(acc + 12, (u32)v1.w, w1);
        qfma4(acc, (u32)v2.x, w2); qfma4(acc + 4, (u32)v2.y, w2);
        qfma4(acc + 8, (u32)v2.z, w2); qfma4(acc + 12, (u32)v2.w, w2);
        qfma4(acc, (u32)v3.x, w3); qfma4(acc + 4, (u32)v3.y, w3);
        qfma4(acc + 8, (u32)v3.z, w3); qfma4(acc + 12, (u32)v3.w, w3);
    }
    for (; e < len; ++e) {
        int s = rowp[e];
        float wv = qs1[s];
        int4 v = *(const int4*)(xq + (size_t)s * F_IN + q * 16);
        qfma4(acc, (u32)v.x, wv); qfma4(acc + 4, (u32)v.y, wv);
        qfma4(acc + 8, (u32)v.z, wv); qfma4(acc + 12, (u32)v.w, wv);
    }
    float dd = dinv[node];
    int4 o0, o1;
    o0.x = (int)((u32)f2bf(acc[0] * dd)  | ((u32)f2bf(acc[1] * dd)  << 16));
    o0.y = (int)((u32)f2bf(acc[2] * dd)  | ((u32)f2bf(acc[3] * dd)  << 16));
    o0.z = (int)((u32)f2bf(acc[4] * dd)  | ((u32)f2bf(acc[5] * dd)  << 16));
    o0.w = (int)((u32)f2bf(acc[6] * dd)  | ((u32)f2bf(acc[7] * dd)  << 16));
    o1.x = (int)((u32)f2bf(acc[8] * dd)  | ((u32)f2bf(acc[9] * dd)  << 16));
    o1.y = (int)((u32)f2bf(acc[10] * dd) | ((u32)f2bf(acc[11] * dd) << 16));
    o1.z = (int)((u32)f2bf(acc[12] * dd) | ((u32)f2bf(acc[13] * dd) << 16));
    o1.w = (int)((u32)f2bf(acc[14] * dd) | ((u32)f2bf(acc[15] * dd) << 16));
    u16* op = aggb + (size_t)node * H_DIM + q * 16;
    *(int4*)op = o0;
    *(int4*)(op + 8) = o1;
}

// ------------- GEMM1 via MFMA: hb = relu(aggb@W1 + b1) (bf16) --------------
__global__ __launch_bounds__(256) void gemm1_mfma(const u16* __restrict__ aggb,
                                                  const u16* __restrict__ W1t,
                                                  const float* __restrict__ b1,
                                                  u16* __restrict__ hb,
                                                  float* __restrict__ pstats) {
    __shared__ u16 As[G1_ROWS * G1_LD];   // 34.8 KB
    int tid = threadIdx.x;
    int base = blockIdx.x * G1_ROWS;

    {   // stage 128 node rows (256 B each), clamped at tail
        int row = tid >> 1, half = tid & 1;
        int gr = base + row; if (gr >= N_NODES) gr = N_NODES - 1;
        const int4* gsrc = (const int4*)(aggb + (size_t)gr * H_DIM + half * 64);
        int4* ldst = (int4*)(As + row * G1_LD + half * 64);
        #pragma unroll
        for (int i = 0; i < 8; ++i) ldst[i] = gsrc[i];
    }
    __syncthreads();

    int lane = tid & 63, w = tid >> 6;
    int r = lane & 15, g = lane >> 4;

    bf16x8 wf[2][4];   // [ch-tile][kstep], resident
    #pragma unroll
    for (int t = 0; t < 2; ++t)
        #pragma unroll
        for (int ks = 0; ks < 4; ++ks)
            wf[t][ks] = *(const bf16x8*)(W1t + (w * 32 + t * 16 + r) * H_DIM + ks * 32 + g * 8);

    float bch[2][4];
    #pragma unroll
    for (int t = 0; t < 2; ++t)
        #pragma unroll
        for (int i = 0; i < 4; ++i)
            bch[t][i] = b1[w * 32 + t * 16 + 4 * g + i];

    float cs[8] = {}, cq[8] = {};

    for (int rt = 0; rt < 8; ++rt) {
        f32x4 acc0 = {0.f, 0.f, 0.f, 0.f}, acc1 = {0.f, 0.f, 0.f, 0.f};
        #pragma unroll
        for (int ks = 0; ks < 4; ++ks) {
            bf16x8 nf = *(const bf16x8*)(As + (rt * 16 + r) * G1_LD + ks * 32 + g * 8);
            acc0 = __builtin_amdgcn_mfma_f32_16x16x32_bf16(wf[0][ks], nf, acc0, 0, 0, 0);
            acc1 = __builtin_amdgcn_mfma_f32_16x16x32_bf16(wf[1][ks], nf, acc1, 0, 0, 0);
        }
        int node = base + rt * 16 + r;
        if (node < N_NODES) {
            float o0[4], o1[4];
            #pragma unroll
            for (int i = 0; i < 4; ++i) {
                o0[i] = fmaxf(acc0[i] + bch[0][i], 0.f);
                o1[i] = fmaxf(acc1[i] + bch[1][i], 0.f);
                cs[i]     += o0[i]; cq[i]     += o0[i] * o0[i];
                cs[4 + i] += o1[i]; cq[4 + i] += o1[i] * o1[i];
            }
            uint2 p0, p1;
            p0.x = (u32)f2bf(o0[0]) | ((u32)f2bf(o0[1]) << 16);
            p0.y = (u32)f2bf(o0[2]) | ((u32)f2bf(o0[3]) << 16);
            p1.x = (u32)f2bf(o1[0]) | ((u32)f2bf(o1[1]) << 16);
            p1.y = (u32)f2bf(o1[2]) | ((u32)f2bf(o1[3]) << 16);
            u16* hp = hb + (size_t)node * H_DIM + w * 32 + 4 * g;
            *(uint2*)hp = p0;
            *(uint2*)(hp + 16) = p1;
        }
    }

    #pragma unroll
    for (int j = 0; j < 8; ++j) {
        #pragma unroll
        for (int m = 1; m < 16; m <<= 1) {
            cs[j] += __shfl_xor(cs[j], m, 16);
            cq[j] += __shfl_xor(cq[j], m, 16);
        }
    }
    if (r == 0) {
        #pragma unroll
        for (int j = 0; j < 8; ++j) {
            int c = w * 32 + (j >> 2) * 16 + 4 * g + (j & 3);
            pstats[c * PS_LD + blockIdx.x] = cs[j];
            pstats[(128 + c) * PS_LD + blockIdx.x] = cq[j];
        }
    }
}

// ---- reduce per-block partials -> scale/shift (one block per channel) ----
__global__ __launch_bounds__(256) void stats_final(const float* __restrict__ pstats,
                                                   const float* __restrict__ gamma,
                                                   const float* __restrict__ beta,
                                                   float* __restrict__ scale,
                                                   float* __restrict__ shift) {
    __shared__ float ls[256], lq[256];
    int c = blockIdx.x, t = threadIdx.x;
    float s = 0.f, q = 0.f;
    for (int b = t; b < G1_NB; b += 256) {
        s += pstats[c * PS_LD + b];
        q += pstats[(128 + c) * PS_LD + b];
    }
    ls[t] = s; lq[t] = q;
    __syncthreads();
    for (int off = 128; off; off >>= 1) {
        if (t < off) { ls[t] += ls[t + off]; lq[t] += lq[t + off]; }
        __syncthreads();
    }
    if (t == 0) {
        const float invn = 1.0f / (float)N_NODES;
        float mean = ls[0] * invn;
        float var = lq[0] * invn - mean * mean;
        float sc = gamma[c] * rsqrtf(var + BN_EPS);
        scale[c] = sc;
        shift[c] = beta[c] - mean * sc;
    }
}

// ---- fold BN into layer-2 weights; one block per padded channel c<48 ----
__global__ __launch_bounds__(128) void w2fold(const float* __restrict__ W2,
                                              const float* __restrict__ scale,
                                              const float* __restrict__ shift,
                                              u16* __restrict__ W2t,
                                              float* __restrict__ K) {
    __shared__ float red[128];
    int c = blockIdx.x, k = threadIdx.x;
    float wv = (c < C_OUT) ? W2[k * C_OUT + c] : 0.f;
    W2t[c * H_DIM + k] = (c < C_OUT) ? f2bf(scale[k] * wv) : (u16)0;
    red[k] = shift[k] * wv;
    __syncthreads();
    for (int off = 64; off; off >>= 1) {
        if (k < off) red[k] += red[k + off];
        __syncthreads();
    }
    if (k == 0) K[c] = red[0];
}

// ---- GEMM2 via MFMA -> int8 row-quantized h2q (64 B rows incl. zero pad) ---
__global__ __launch_bounds__(256) void gemm2_mfma(const u16* __restrict__ hb,
                                                  const u16* __restrict__ W2t,
                                                  const float* __restrict__ K,
                                                  const float* __restrict__ dinv,
                                                  s8* __restrict__ h2q,
                                                  float* __restrict__ srow2) {
    __shared__ u16 As[G2_ROWS * G1_LD];
    int tid = threadIdx.x;
    int base = blockIdx.x * G2_ROWS;

    {
        int row = tid >> 1, half = tid & 1;
        int gr = base + row; if (gr >= N_NODES) gr = N_NODES - 1;
        const int4* gsrc = (const int4*)(hb + (size_t)gr * H_DIM + half * 64);
        int4* ldst = (int4*)(As + row * G1_LD + half * 64);
        #pragma unroll
        for (int i = 0; i < 8; ++i) ldst[i] = gsrc[i];
    }
    __syncthreads();

    int lane = tid & 63, w = tid >> 6;
    int r = lane & 15, g = lane >> 4;

    bf16x8 wf[3][4];
    #pragma unroll
    for (int t = 0; t < 3; ++t)
        #pragma unroll
        for (int ks = 0; ks < 4; ++ks)
            wf[t][ks] = *(const bf16x8*)(W2t + (t * 16 + r) * H_DIM + ks * 32 + g * 8);

    float kv[3][4];
    #pragma unroll
    for (int t = 0; t < 3; ++t)
        #pragma unroll
        for (int i = 0; i < 4; ++i)
            kv[t][i] = K[t * 16 + 4 * g + i];

    f32x4 acc[2][3];
    #pragma unroll
    for (int i2 = 0; i2 < 2; ++i2)
        #pragma unroll
        for (int t = 0; t < 3; ++t)
            acc[i2][t] = (f32x4){0.f, 0.f, 0.f, 0.f};

    #pragma unroll
    for (int i2 = 0; i2 < 2; ++i2) {
        int rt = 2 * w + i2;
        #pragma unroll
        for (int ks = 0; ks < 4; ++ks) {
            bf16x8 nf = *(const bf16x8*)(As + (rt * 16 + r) * G1_LD + ks * 32 + g * 8);
            acc[i2][0] = __builtin_amdgcn_mfma_f32_16x16x32_bf16(wf[0][ks], nf, acc[i2][0], 0, 0, 0);
            acc[i2][1] = __builtin_amdgcn_mfma_f32_16x16x32_bf16(wf[1][ks], nf, acc[i2][1], 0, 0, 0);
            acc[i2][2] = __builtin_amdgcn_mfma_f32_16x16x32_bf16(wf[2][ks], nf, acc[i2][2], 0, 0, 0);
        }
    }

    #pragma unroll
    for (int i2 = 0; i2 < 2; ++i2) {
        int node = base + (2 * w + i2) * 16 + r;
        float dd = (node < N_NODES) ? dinv[node] : 0.f;
        float v[3][4];
        float m = 0.f;
        #pragma unroll
        for (int t = 0; t < 3; ++t)
            #pragma unroll
            for (int i = 0; i < 4; ++i) {
                v[t][i] = (acc[i2][t][i] + kv[t][i]) * dd;
                if (t < 2 || g < 2) m = fmaxf(m, fabsf(v[t][i]));
            }
        m = fmaxf(m, __shfl_xor(m, 16));     // across g pairs
        m = fmaxf(m, __shfl_xor(m, 32));
        m = fmaxf(m, 1e-20f);
        float inv = 127.f / m;
        if (node < N_NODES) {
            s8* hp = h2q + (size_t)node * H2_B;
            #pragma unroll
            for (int t = 0; t < 2; ++t) {
                u32 p = pack4((int)rintf(v[t][0] * inv), (int)rintf(v[t][1] * inv),
                              (int)rintf(v[t][2] * inv), (int)rintf(v[t][3] * inv));
                *(u32*)(hp + t * 16 + 4 * g) = p;
            }
            u32 p2 = (g < 2) ? pack4((int)rintf(v[2][0] * inv), (int)rintf(v[2][1] * inv),
                                     (int)rintf(v[2][2] * inv), (int)rintf(v[2][3] * inv))
                             : 0u;
            *(u32*)(hp + 32 + 4 * g) = p2;       // g>=2 zeroes ch 40-47
            *(u32*)(hp + 48 + 4 * g) = 0u;       // ch 48-63 zero
            if (g == 0) srow2[node] = m / 127.f;
        }
    }
}

// --- gather layer 2 (int8): out = logsoftmax(dinv[n]*sum srow2[s]*h2q[s]+b2)
// 8 lanes/node (8 ch each, uint2 = 8 B), 32 nodes/block, 4-edge unroll.
// Valid channels live in lanes q<5 (5*8 = 40).
__global__ __launch_bounds__(256) void gather2_fused(const int* __restrict__ cnt,
                                                     const int* __restrict__ ell,
                                                     const float* __restrict__ dinv,
                                                     const float* __restrict__ srow2,
                                                     const s8* __restrict__ h2q,
                                                     const float* __restrict__ b2,
                                                     float* __restrict__ out) {
    int node = blockIdx.x * 32 + (threadIdx.x >> 3);     // grid exact: N%32==0
    int q = threadIdx.x & 7;
    int len = cnt[node];
    const int* rowp = ell + (size_t)node * ELL_W;
    float acc[8] = {};
    int e = 0;
    for (; e + 3 < len; e += 4) {
        int s0 = rowp[e], s1 = rowp[e + 1], s2 = rowp[e + 2], s3 = rowp[e + 3];
        float w0 = srow2[s0], w1 = srow2[s1], w2 = srow2[s2], w3 = srow2[s3];
        uint2 d0 = *(const uint2*)(h2q + (size_t)s0 * H2_B + q * 8);
        uint2 d1 = *(const uint2*)(h2q + (size_t)s1 * H2_B + q * 8);
        uint2 d2 = *(const uint2*)(h2q + (size_t)s2 * H2_B + q * 8);
        uint2 d3 = *(const uint2*)(h2q + (size_t)s3 * H2_B + q * 8);
        qfma4(acc, d0.x, w0); qfma4(acc + 4, d0.y, w0);
        qfma4(acc, d1.x, w1); qfma4(acc + 4, d1.y, w1);
        qfma4(acc, d2.x, w2); qfma4(acc + 4, d2.y, w2);
        qfma4(acc, d3.x, w3); qfma4(acc + 4, d3.y, w3);
    }
    for (; e < len; ++e) {
        int s = rowp[e];
        float wv = srow2[s];
        uint2 d = *(const uint2*)(h2q + (size_t)s * H2_B + q * 8);
        qfma4(acc, d.x, wv); qfma4(acc + 4, d.y, wv);
    }
    float dd = dinv[node];
    float r[8];
    float m = -INFINITY;
    if (q < 5) {
        float4 bv0 = *(const float4*)(b2 + q * 8);
        float4 bv1 = *(const float4*)(b2 + q * 8 + 4);
        r[0] = fmaf(acc[0], dd, bv0.x); r[1] = fmaf(acc[1], dd, bv0.y);
        r[2] = fmaf(acc[2], dd, bv0.z); r[3] = fmaf(acc[3], dd, bv0.w);
        r[4] = fmaf(acc[4], dd, bv1.x); r[5] = fmaf(acc[5], dd, bv1.y);
        r[6] = fmaf(acc[6], dd, bv1.z); r[7] = fmaf(acc[7], dd, bv1.w);
        #pragma unroll
        for (int i = 0; i < 8; ++i) m = fmaxf(m, r[i]);
    }
    #pragma unroll
    for (int off = 1; off < 8; off <<= 1) m = fmaxf(m, __shfl_xor(m, off, 8));
    float ex = 0.f;
    if (q < 5) {
        #pragma unroll
        for (int i = 0; i < 8; ++i) ex += expf(r[i] - m);
    }
    #pragma unroll
    for (int off = 1; off < 8; off <<= 1) ex += __shfl_xor(ex, off, 8);
    float lse = logf(ex) + m;
    if (q < 5) {
        float4 o0 = {r[0] - lse, r[1] - lse, r[2] - lse, r[3] - lse};
        float4 o1 = {r[4] - lse, r[5] - lse, r[6] - lse, r[7] - lse};
        float* op = out + (size_t)node * C_OUT + q * 8;
        *(float4*)op = o0;
        *(float4*)(op + 4) = o1;
    }
}

// ---------------- launch ----------------
extern "C" void kernel_launch(void* const* d_in, const int* in_sizes, int n_in,
                              void* d_out, int out_size, void* d_ws, size_t ws_size,
                              hipStream_t stream) {
    const float* x     = (const float*)d_in[0];
    const int*   eidx  = (const int*)d_in[1];
    const float* W1    = (const float*)d_in[2];
    const float* b1    = (const float*)d_in[3];
    const float* gamma = (const float*)d_in[4];
    const float* beta  = (const float*)d_in[5];
    const float* W2    = (const float*)d_in[6];
    const float* b2    = (const float*)d_in[7];
    float* out = (float*)d_out;

    const int* src = eidx;
    const int* dst = eidx + N_EDGES;

    // workspace layout (dword units)
    float* ws = (float*)d_ws;
    float* dinv    = ws;                        // N
    int*   cnt     = (int*)(ws + 100000);       // N
    int*   bcur    = (int*)(ws + 200000);       // NBKT*16 (+pad)
    int*   ell     = (int*)(ws + 203200);       // N*64 = 6.4M
    s8*    xq      = (s8*)(ws + 6603200);       // N*128 int8 = 3.2M dwords
    float* qs1     = ws + 9803200;              // N   (s_row -> qscale1 in place)
    float* srow2   = ws + 9903200;              // N
    u16*   aggb    = (u16*)(ws + 10003200);     // N*128 bf16 = 6.4M dwords
    u32*   region  = (u32*)(ws + 10003200);     // aliases aggb: NBKT*BKT_CAP u32 = 2.41M dwords
    u16*   hb      = (u16*)(ws + 16403200);     // N*128 bf16 = 6.4M dwords
    u16*   W1t     = (u16*)(ws + 22803200);     // 8192 dwords
    s8*    h2q     = (s8*)(ws + 22811392);      // N*64 int8 = 1.6M dwords
    float* pstats  = ws + 24411392;             // 256*800
    float* scale   = ws + 24616192;             // 128
    float* shift   = ws + 24616320;             // 128
    float* K       = ws + 24616448;             // 64
    u16*   W2t     = (u16*)(ws + 24616512);     // 3072 dwords

    size_t needed = (size_t)(24616512 + 3072 + 256) * 4;   // ~98.5 MB (<= 99.2 proven)
    if (ws_size < needed) return;

    // prep: x-quant + wconvert overlap the sorted bucket scatter in one kernel
    hipMemsetAsync(bcur, 0, NBKT * CNT_STRIDE * 4, stream);
    fused_prep<<<P_NB + FP_WCV_NB + FP_XQ_NB, 256, 0, stream>>>(
        x, W1, src, dst, bcur, region, xq, qs1, W1t);
    ell_build<<<NBKT, 256, 0, stream>>>(bcur, region, ell, cnt, dinv, qs1);

    // layer 1
    gather_x<<<N_NODES / 32, 256, 0, stream>>>(cnt, ell, dinv, qs1, xq, aggb);
    gemm1_mfma<<<G1_NB, 256, 0, stream>>>(aggb, W1t, b1, hb, pstats);
    stats_final<<<128, 256, 0, stream>>>(pstats, gamma, beta, scale, shift);
    w2fold<<<48, 128, 0, stream>>>(W2, scale, shift, W2t, K);

    // layer 2
    gemm2_mfma<<<G2_NB, 256, 0, stream>>>(hb, W2t, K, dinv, h2q, srow2);
    gather2_fused<<<N_NODES / 32, 256, 0, stream>>>(cnt, ell, dinv, srow2, h2q, b2, out);
}